// Round 1
// baseline (248.172 us; speedup 1.0000x reference)
//
#include <hip/hip_runtime.h>
#include <math.h>

#define Hh 128
#define Ww 128
#define Dd 256
#define Bb 4
#define HW (Hh*Ww)        // 16384
#define NPIX (Bb*HW)      // 65536
#define WP 140            // padded width/height (6-px zero ring for fused conv pyramid)

typedef __attribute__((ext_vector_type(8))) short s16x8;   // 8 bf16 (4 VGPRs)
typedef __attribute__((ext_vector_type(4))) float f32x4;

__device__ __forceinline__ unsigned short f2bf(float f) {
    unsigned u = __float_as_uint(f);
    u += 0x7FFF + ((u >> 16) & 1);
    return (unsigned short)(u >> 16);
}

__device__ __forceinline__ float gelu_exact(float v) {
    return 0.5f * v * (1.0f + erff(v * 0.70710678118654752f));
}

// ---------- K0: zero padded activation buffer + transpose conv weights ----------
// xb = 4*140*140 px * 64ch * 2B = 10,035,200 B = 627,200 uint4
#define ZGRAN 627200
__global__ __launch_bounds__(256) void setup_fill(const float* __restrict__ w0,
                                                  const float* __restrict__ w1,
                                                  const float* __restrict__ w2,
                                                  unsigned short* __restrict__ wb0,
                                                  unsigned short* __restrict__ wb1,
                                                  unsigned short* __restrict__ wb2,
                                                  uint4* __restrict__ zbase) {
    int t = blockIdx.x * 256 + threadIdx.x;
    if (t < ZGRAN) {
        zbase[t] = (uint4){0, 0, 0, 0};
        return;
    }
    int u = t - ZGRAN;
    if (u < 51200) {
        int tap = u >> 11; int r = u & 2047; int n = r >> 6; int k = r & 63;
        wb0[u] = (k < 52) ? f2bf(w0[n * 1300 + k * 25 + tap]) : (unsigned short)0;
    } else if (u < 76800) {
        int v = u - 51200; int tap = v >> 10; int r = v & 1023; int n = r >> 5; int k = r & 31;
        wb1[v] = f2bf(w1[n * 800 + k * 25 + tap]);
    } else if (u < 89600) {
        int v = u - 76800; int tap = v >> 9; int r = v & 511; int n = r >> 5; int k = r & 31;
        wb2[v] = (n < 2) ? f2bf(w2[n * 800 + k * 25 + tap]) : (unsigned short)0;
    }
}

// ---------- K1: fused normalize, 16-lane groups (4 pixels/wave) ----------
// blocks 0..4095: vis -> kn ; blocks 4096..8191: rubin bilinear -> qn
__global__ __launch_bounds__(256) void norm_fused(const float* __restrict__ vis,
                                                  const float* __restrict__ rub,
                                                  unsigned short* __restrict__ kn,
                                                  unsigned short* __restrict__ qn) {
    int tid = threadIdx.x;
    int g16 = tid >> 4, l = tid & 15;
    int blk = blockIdx.x;
    if (blk < 4096) {
        int pix = blk * 16 + g16;
        const float* base = vis + (size_t)pix * Dd + l * 4;
        float4 v[4];
#pragma unroll
        for (int i = 0; i < 4; i++) v[i] = *(const float4*)(base + i * 64);
        float ss = 0.f;
#pragma unroll
        for (int i = 0; i < 4; i++)
            ss += v[i].x * v[i].x + v[i].y * v[i].y + v[i].z * v[i].z + v[i].w * v[i].w;
#pragma unroll
        for (int o = 1; o <= 8; o <<= 1) ss += __shfl_xor(ss, o, 64);
        float inv = __builtin_amdgcn_rsqf(fmaxf(ss, 1e-24f));
        unsigned short* op = kn + (size_t)pix * Dd + l * 4;
#pragma unroll
        for (int i = 0; i < 4; i++) {
            ushort4 o4;
            o4.x = f2bf(v[i].x * inv); o4.y = f2bf(v[i].y * inv);
            o4.z = f2bf(v[i].z * inv); o4.w = f2bf(v[i].w * inv);
            *(ushort4*)(op + i * 64) = o4;
        }
    } else {
        int pix = (blk - 4096) * 16 + g16;
        int b = pix >> 14; int yx = pix & 16383; int y = yx >> 7; int x = yx & 127;
        float sy = 0.5f * y - 0.25f;
        float sx = 0.5f * x - 0.25f;
        int y0 = (int)floorf(sy); float fy = sy - (float)y0;
        int x0 = (int)floorf(sx); float fx = sx - (float)x0;
        int y0c = max(y0, 0), y1c = min(y0 + 1, 63);
        int x0c = max(x0, 0), x1c = min(x0 + 1, 63);
        const float* base = rub + (size_t)b * 4096 * Dd + l * 4;
        const float* p00 = base + (size_t)(y0c * 64 + x0c) * Dd;
        const float* p01 = base + (size_t)(y0c * 64 + x1c) * Dd;
        const float* p10 = base + (size_t)(y1c * 64 + x0c) * Dd;
        const float* p11 = base + (size_t)(y1c * 64 + x1c) * Dd;
        float w00 = (1.f - fy) * (1.f - fx), w01 = (1.f - fy) * fx;
        float w10 = fy * (1.f - fx), w11 = fy * fx;
        float4 bv[4];
        float ss = 0.f;
#pragma unroll
        for (int i = 0; i < 4; i++) {
            float4 a = *(const float4*)(p00 + i * 64);
            float4 b1 = *(const float4*)(p01 + i * 64);
            float4 c = *(const float4*)(p10 + i * 64);
            float4 d = *(const float4*)(p11 + i * 64);
            float4 v;
            v.x = w00 * a.x + w01 * b1.x + w10 * c.x + w11 * d.x;
            v.y = w00 * a.y + w01 * b1.y + w10 * c.y + w11 * d.y;
            v.z = w00 * a.z + w01 * b1.z + w10 * c.z + w11 * d.z;
            v.w = w00 * a.w + w01 * b1.w + w10 * c.w + w11 * d.w;
            bv[i] = v;
            ss += v.x * v.x + v.y * v.y + v.z * v.z + v.w * v.w;
        }
#pragma unroll
        for (int o = 1; o <= 8; o <<= 1) ss += __shfl_xor(ss, o, 64);
        float inv = __builtin_amdgcn_rsqf(fmaxf(ss, 1e-24f));
        unsigned short* op = qn + (size_t)pix * Dd + l * 4;
#pragma unroll
        for (int i = 0; i < 4; i++) {
            ushort4 o4;
            o4.x = f2bf(bv[i].x * inv); o4.y = f2bf(bv[i].y * inv);
            o4.z = f2bf(bv[i].z * inv); o4.w = f2bf(bv[i].w * inv);
            *(ushort4*)(op + i * 64) = o4;
        }
    }
}

// ---------- K2: 2D-tiled LDS corr + shuffle softmax (xb ring now 6) ----------
__global__ __launch_bounds__(1024) void corr_block(const unsigned short* __restrict__ qn,
                                                   const unsigned short* __restrict__ kn,
                                                   const float* __restrict__ log_temp,
                                                   unsigned short* __restrict__ xb,
                                                   float* __restrict__ out) {
    __shared__ char smem[484 * 5 * 16];
    int tid = threadIdx.x;
    int wid = tid >> 6, lane = tid & 63, l15 = lane & 15, quad = lane >> 4;
    int blk = blockIdx.x;
    int b = blk >> 6, rem = blk & 63;
    int y0 = ((rem >> 3) & 7) << 4, x0 = (rem & 7) << 4;
    int y = y0 + wid;

    const unsigned short* src0; int dst0;
    const unsigned short* src1 = nullptr; int dst1 = 0;
    bool hav1;
    {
        int g = tid;
        int px = g >> 2, sub = g & 3;
        int ry = px / 22, rx = px - ry * 22;
        int yy = min(max(y0 - 3 + ry, 0), 127);
        int xx = min(max(x0 - 3 + rx, 0), 127);
        src0 = kn + ((size_t)(b << 14) + yy * 128 + xx) * 256 + sub * 8;
        dst0 = (px * 5 + sub) * 16;
        g = 1024 + tid;
        hav1 = (g < 1936);
        int gc = hav1 ? g : 1935;
        px = gc >> 2; sub = gc & 3;
        ry = px / 22; rx = px - ry * 22;
        yy = min(max(y0 - 3 + ry, 0), 127);
        xx = min(max(x0 - 3 + rx, 0), 127);
        src1 = kn + ((size_t)(b << 14) + yy * 128 + xx) * 256 + sub * 8;
        dst1 = (px * 5 + sub) * 16;
    }
    int lpixoff[10];
#pragma unroll
    for (int f = 0; f < 10; f++) {
        int p = min(f * 16 + l15, 153);
        int pr = p / 22, pc = p - pr * 22;
        lpixoff[f] = (((wid + pr) * 22 + pc) * 5 + quad) * 16;
    }
    const unsigned short* aptr = qn + ((size_t)(b << 14) + y * 128 + x0 + l15) * 256 + quad * 8;

    f32x4 acc[10];
#pragma unroll
    for (int f = 0; f < 10; f++) acc[f] = (f32x4){0.f, 0.f, 0.f, 0.f};

    uint4 v0 = *(const uint4*)src0;
    uint4 v1 = *(const uint4*)src1;
    s16x8 an = *(const s16x8*)aptr;
    for (int c = 0; c < 8; c++) {
        uint4 w0v = v0, w1v = v1;
        s16x8 a = an;
        if (c < 7) {
            v0 = *(const uint4*)(src0 + (c + 1) * 32);
            v1 = *(const uint4*)(src1 + (c + 1) * 32);
            an = *(const s16x8*)(aptr + (c + 1) * 32);
        }
        __syncthreads();
        *(uint4*)(smem + dst0) = w0v;
        if (hav1) *(uint4*)(smem + dst1) = w1v;
        __syncthreads();
#pragma unroll
        for (int f = 0; f < 10; f++) {
            s16x8 bf = *(const s16x8*)(smem + lpixoff[f]);
            acc[f] = __builtin_amdgcn_mfma_f32_16x16x32_bf16(a, bf, acc[f], 0, 0, 0);
        }
    }

    float inv_temp = expf(-log_temp[0]);
    float vmax[4] = {-1e30f, -1e30f, -1e30f, -1e30f};
#pragma unroll
    for (int f = 0; f < 10; f++) {
        int n = f * 16 + l15;
        if (n <= 153) {
            int dy = n / 22 - 3;
            int rx = n - (dy + 3) * 22;
#pragma unroll
            for (int i = 0; i < 4; i++) {
                int m = quad * 4 + i;
                int dx = rx - m - 3;
                if ((unsigned)(dx + 3) <= 6u) vmax[i] = fmaxf(vmax[i], acc[f][i]);
            }
        }
    }
#pragma unroll
    for (int o = 1; o <= 8; o <<= 1) {
#pragma unroll
        for (int i = 0; i < 4; i++) vmax[i] = fmaxf(vmax[i], __shfl_xor(vmax[i], o, 64));
    }
    float se[4] = {0, 0, 0, 0}, sey[4] = {0, 0, 0, 0}, sex[4] = {0, 0, 0, 0}, emax[4] = {0, 0, 0, 0};
    unsigned short* xrow = xb + ((size_t)(b * WP + y + 6) * WP + x0 + 6) * 64;
#pragma unroll
    for (int f = 0; f < 10; f++) {
        int n = f * 16 + l15;
        if (n <= 153) {
            int dy = n / 22 - 3;
            int rx = n - (dy + 3) * 22;
#pragma unroll
            for (int i = 0; i < 4; i++) {
                int m = quad * 4 + i;
                int dx = rx - m - 3;
                if ((unsigned)(dx + 3) <= 6u) {
                    float v = acc[f][i];
                    float e = expf((v - vmax[i]) * inv_temp);
                    se[i] += e;
                    sey[i] += e * (float)dy;
                    sex[i] += e * (float)dx;
                    emax[i] = fmaxf(emax[i], e);
                    xrow[(size_t)m * 64 + 2 + (dy + 3) * 7 + (dx + 3)] = f2bf(v);
                }
            }
        }
    }
#pragma unroll
    for (int o = 1; o <= 8; o <<= 1) {
#pragma unroll
        for (int i = 0; i < 4; i++) {
            se[i] += __shfl_xor(se[i], o, 64);
            sey[i] += __shfl_xor(sey[i], o, 64);
            sex[i] += __shfl_xor(sex[i], o, 64);
            emax[i] = fmaxf(emax[i], __shfl_xor(emax[i], o, 64));
        }
    }
    if (l15 == 0) {
#pragma unroll
        for (int i = 0; i < 4; i++) {
            int m = quad * 4 + i;
            float inv_se = 1.0f / se[i];
            float dyv = sey[i] * inv_se, dxv = sex[i] * inv_se, conf = emax[i] * inv_se;
            unsigned short* xp = xrow + (size_t)m * 64;
            xp[0] = f2bf(dyv); xp[1] = f2bf(dxv); xp[51] = f2bf(conf);
            float* op = out + (size_t)b * 5 * HW + y * 128 + x0 + m;
            op[2 * HW] = dyv; op[3 * HW] = dxv; op[4 * HW] = conf;
        }
    }
}

// ---------- K3: fused conv pyramid (conv1 -> gelu -> conv2 -> gelu -> final + residual) ----------
// Per 16x16 output tile: stage x on 28x28 (6-halo from zero ring), compute h1 24x24 and
// h2 20x20 entirely in LDS (halo recompute), final 16x16 -> out with residual+sky scale.
// LDS: X 50176 + Wchunk 26624 + h1 36864 + h2 25600 = 139264 B. XOR-granule swizzle
// (g ^= (px>>1)&3) gives 2-way (free) bank access for all b128 reads.
__global__ __launch_bounds__(1024) void conv_pyramid(const unsigned short* __restrict__ xb,
                                                     const unsigned short* __restrict__ wb0,
                                                     const float* __restrict__ b0,
                                                     const unsigned short* __restrict__ wb1,
                                                     const float* __restrict__ b1,
                                                     const unsigned short* __restrict__ wb2,
                                                     const float* __restrict__ b2,
                                                     float* __restrict__ out) {
    constexpr int XBYTES = 784 * 64;      // 28*28 px, 32ch chunk
    constexpr int WBYTES = 13 * 32 * 64;  // up to 13 taps * 32 oc * 32ch
    constexpr int H1BYTES = 576 * 64;     // 24*24 px * 32ch
    constexpr int H2BYTES = 400 * 64;     // 20*20 px * 32ch
    __shared__ char smem[XBYTES + WBYTES + H1BYTES + H2BYTES];
    char* sX = smem;
    char* sW = smem + XBYTES;
    char* sH1 = smem + XBYTES + WBYTES;
    char* sH2 = sH1 + H1BYTES;

    int tid = threadIdx.x;
    int wv = tid >> 6, lane = tid & 63, l15 = lane & 15, quad = lane >> 4;
    int blk = blockIdx.x;
    int b = blk >> 6, ty = (blk >> 3) & 7, tx = blk & 7;
    int y0 = ty * 16, x0 = tx * 16;

    // ---- staging helpers ----
    auto stage_x = [&](int ks) {
#pragma unroll
        for (int i = 0; i < 4; i++) {
            int g = i * 1024 + tid;
            if (g < 3136) {
                int px = g >> 2, sub = g & 3;
                int r = px / 28, c = px - r * 28;
                *(uint4*)(sX + px * 64 + ((sub ^ ((px >> 1) & 3)) << 4)) =
                    *(const uint4*)(xb + ((size_t)(b * WP + y0 + r) * WP + x0 + c) * 64 + ks * 32 + sub * 8);
            }
        }
    };
    auto stage_w = [&](const unsigned short* src, int rows, int rlen, int choff) {
        int ngr = rows * 4;
        for (int i = 0; i * 1024 < ngr; i++) {
            int g = i * 1024 + tid;
            if (g < ngr) {
                int nl = g >> 2, sub = g & 3;
                *(uint4*)(sW + nl * 64 + ((sub ^ ((nl >> 1) & 3)) << 4)) =
                    *(const uint4*)(src + (size_t)nl * rlen + choff + sub * 8);
            }
        }
    };

    // ---- conv1: x(64ch) -> h1(32ch), 24x24, units = 24 rows x 2 col-segments = 48 ----
    f32x4 acc1[3][2];
#pragma unroll
    for (int s = 0; s < 3; s++) { acc1[s][0] = (f32x4){0,0,0,0}; acc1[s][1] = (f32x4){0,0,0,0}; }

    auto conv1_half = [&](int tap0, int nt) {
        for (int t = 0; t < nt; t++) {
            int tap = tap0 + t;
            int ky = tap / 5, kx = tap - ky * 5;
            int lr0 = t * 32 + l15;
            s16x8 wf0 = *(const s16x8*)(sW + lr0 * 64 + ((quad ^ ((lr0 >> 1) & 3)) << 4));
            int lr1 = lr0 + 16;
            s16x8 wf1 = *(const s16x8*)(sW + lr1 * 64 + ((quad ^ ((lr1 >> 1) & 3)) << 4));
#pragma unroll
            for (int s = 0; s < 3; s++) {
                int u = s * 16 + wv;
                int r = u >> 1, cb = (u & 1) << 4;
                int px = (r + ky) * 28 + min(cb + l15 + kx, 27);
                s16x8 a = *(const s16x8*)(sX + px * 64 + ((quad ^ ((px >> 1) & 3)) << 4));
                acc1[s][0] = __builtin_amdgcn_mfma_f32_16x16x32_bf16(a, wf0, acc1[s][0], 0, 0, 0);
                acc1[s][1] = __builtin_amdgcn_mfma_f32_16x16x32_bf16(a, wf1, acc1[s][1], 0, 0, 0);
            }
        }
    };

    stage_x(0); stage_w(wb0, 13 * 32, 64, 0);
    __syncthreads();
    conv1_half(0, 13);
    __syncthreads();
    stage_w(wb0 + 13 * 32 * 64, 12 * 32, 64, 0);
    __syncthreads();
    conv1_half(13, 12);
    __syncthreads();
    stage_x(1); stage_w(wb0, 13 * 32, 64, 32);
    __syncthreads();
    conv1_half(0, 13);
    __syncthreads();
    stage_w(wb0 + 13 * 32 * 64, 12 * 32, 64, 32);
    __syncthreads();
    conv1_half(13, 12);

    // write h1 (bias + gelu, zero outside image => SAME-pad semantics for conv2)
#pragma unroll
    for (int s = 0; s < 3; s++) {
        int u = s * 16 + wv;
        int r = u >> 1, cb = (u & 1) << 4;
        int ay = y0 + r - 4;
#pragma unroll
        for (int g = 0; g < 2; g++) {
            float bv = b0[g * 16 + l15];
#pragma unroll
            for (int rr = 0; rr < 4; rr++) {
                int col = cb + quad * 4 + rr;
                if (col < 24) {
                    float v = gelu_exact(acc1[s][g][rr] + bv);
                    int ax = x0 + col - 4;
                    unsigned short o = ((unsigned)ay < 128u && (unsigned)ax < 128u) ? f2bf(v)
                                                                                    : (unsigned short)0;
                    int px = r * 24 + col;
                    int gran = g * 2 + (l15 >> 3);
                    *(unsigned short*)(sH1 + px * 64 + ((gran ^ ((px >> 1) & 3)) << 4) + (l15 & 7) * 2) = o;
                }
            }
        }
    }
    __syncthreads();

    // ---- conv2: h1(32ch) -> h2(32ch), 20x20, units = 20 rows x 2 segs = 40 ----
    f32x4 acc2[3][2];
#pragma unroll
    for (int s = 0; s < 3; s++) { acc2[s][0] = (f32x4){0,0,0,0}; acc2[s][1] = (f32x4){0,0,0,0}; }

    auto conv2_half = [&](int tap0, int nt) {
        for (int t = 0; t < nt; t++) {
            int tap = tap0 + t;
            int ky = tap / 5, kx = tap - ky * 5;
            int lr0 = t * 32 + l15;
            s16x8 wf0 = *(const s16x8*)(sW + lr0 * 64 + ((quad ^ ((lr0 >> 1) & 3)) << 4));
            int lr1 = lr0 + 16;
            s16x8 wf1 = *(const s16x8*)(sW + lr1 * 64 + ((quad ^ ((lr1 >> 1) & 3)) << 4));
#pragma unroll
            for (int s = 0; s < 3; s++) {
                int u = s * 16 + wv;
                if (u < 40) {
                    int r = u >> 1, cb = (u & 1) << 4;
                    int px = (r + ky) * 24 + min(cb + l15 + kx, 23);
                    s16x8 a = *(const s16x8*)(sH1 + px * 64 + ((quad ^ ((px >> 1) & 3)) << 4));
                    acc2[s][0] = __builtin_amdgcn_mfma_f32_16x16x32_bf16(a, wf0, acc2[s][0], 0, 0, 0);
                    acc2[s][1] = __builtin_amdgcn_mfma_f32_16x16x32_bf16(a, wf1, acc2[s][1], 0, 0, 0);
                }
            }
        }
    };

    stage_w(wb1, 13 * 32, 32, 0);
    __syncthreads();
    conv2_half(0, 13);
    __syncthreads();
    stage_w(wb1 + 13 * 32 * 32, 12 * 32, 32, 0);
    __syncthreads();
    conv2_half(13, 12);

    // write h2 (bias + gelu, zero outside image)
#pragma unroll
    for (int s = 0; s < 3; s++) {
        int u = s * 16 + wv;
        if (u < 40) {
            int r = u >> 1, cb = (u & 1) << 4;
            int ay = y0 + r - 2;
#pragma unroll
            for (int g = 0; g < 2; g++) {
                float bv = b1[g * 16 + l15];
#pragma unroll
                for (int rr = 0; rr < 4; rr++) {
                    int col = cb + quad * 4 + rr;
                    if (col < 20) {
                        float v = gelu_exact(acc2[s][g][rr] + bv);
                        int ax = x0 + col - 2;
                        unsigned short o = ((unsigned)ay < 128u && (unsigned)ax < 128u) ? f2bf(v)
                                                                                        : (unsigned short)0;
                        int px = r * 20 + col;
                        int gran = g * 2 + (l15 >> 3);
                        *(unsigned short*)(sH2 + px * 64 + ((gran ^ ((px >> 1) & 3)) << 4) + (l15 & 7) * 2) = o;
                    }
                }
            }
        }
    }
    __syncthreads();

    // ---- final: h2(32ch) -> 2ch (OC padded 16), 16x16, wave = 1 row ----
    stage_w(wb2, 400, 32, 0);   // all 25 taps, 25600 B
    __syncthreads();

    f32x4 acc3 = (f32x4){0, 0, 0, 0};
    for (int t = 0; t < 25; t++) {
        int ky = t / 5, kx = t - ky * 5;
        int px = (wv + ky) * 20 + l15 + kx;
        s16x8 a = *(const s16x8*)(sH2 + px * 64 + ((quad ^ ((px >> 1) & 3)) << 4));
        int lr = t * 16 + l15;
        s16x8 wf = *(const s16x8*)(sW + lr * 64 + ((quad ^ ((lr >> 1) & 3)) << 4));
        acc3 = __builtin_amdgcn_mfma_f32_16x16x32_bf16(a, wf, acc3, 0, 0, 0);
    }

    if (l15 < 2) {
        float bv = b2[l15];
#pragma unroll
        for (int rr = 0; rr < 4; rr++) {
            int m = quad * 4 + rr;
            size_t p5 = (size_t)b * 5 * HW + (y0 + wv) * Ww + x0 + m;
            float a = acc3[rr] + bv;
            if (l15 == 0) {
                out[p5 + HW] = (out[p5 + 2 * HW] + a) * 1.6f;   // ddec
            } else {
                out[p5] = (out[p5 + 3 * HW] + a) * 1.6f;        // dra
            }
        }
    }
}

extern "C" void kernel_launch(void* const* d_in, const int* in_sizes, int n_in,
                              void* d_out, int out_size, void* d_ws, size_t ws_size,
                              hipStream_t stream) {
    const float* rub = (const float*)d_in[0];
    const float* vis = (const float*)d_in[1];
    const float* w0 = (const float*)d_in[2];
    const float* b0 = (const float*)d_in[3];
    const float* w1 = (const float*)d_in[4];
    const float* b1 = (const float*)d_in[5];
    const float* w2 = (const float*)d_in[6];
    const float* b2 = (const float*)d_in[7];
    const float* log_temp = (const float*)d_in[8];
    float* out = (float*)d_out;

    char* ws = (char*)d_ws;
    size_t off = 0;
    const size_t PADPIX = (size_t)Bb * WP * WP;     // 78,400
    unsigned short* kn = (unsigned short*)(ws + off); off += (size_t)NPIX * Dd * 2;
    unsigned short* qn = (unsigned short*)(ws + off); off += (size_t)NPIX * Dd * 2;
    unsigned short* xbp = (unsigned short*)(ws + off); off += PADPIX * 64 * 2;
    unsigned short* wb0 = (unsigned short*)(ws + off); off += 51200 * 2;
    unsigned short* wb1 = (unsigned short*)(ws + off); off += 25600 * 2;
    unsigned short* wb2 = (unsigned short*)(ws + off); off += 12800 * 2;

    setup_fill<<<2800, 256, 0, stream>>>(w0, w1, w2, wb0, wb1, wb2, (uint4*)xbp);
    norm_fused<<<8192, 256, 0, stream>>>(vis, rub, kn, qn);
    corr_block<<<256, 1024, 0, stream>>>(qn, kn, log_temp, xbp, out);
    conv_pyramid<<<256, 1024, 0, stream>>>(xbp, wb0, b0, wb1, b1, wb2, b2, out);
}

// Round 2
// 215.704 us; speedup vs baseline: 1.1505x; 1.1505x over previous
//
#include <hip/hip_runtime.h>
#include <math.h>

#define Hh 128
#define Ww 128
#define Dd 256
#define Bb 4
#define HW (Hh*Ww)        // 16384
#define NPIX (Bb*HW)      // 65536
#define WP 132            // padded width/height (2-px zero ring)

typedef __attribute__((ext_vector_type(8))) short s16x8;   // 8 bf16 (4 VGPRs)
typedef __attribute__((ext_vector_type(4))) float f32x4;

__device__ __forceinline__ unsigned short f2bf(float f) {
    unsigned u = __float_as_uint(f);
    u += 0x7FFF + ((u >> 16) & 1);
    return (unsigned short)(u >> 16);
}

__device__ __forceinline__ float gelu_exact(float v) {
    return 0.5f * v * (1.0f + erff(v * 0.70710678118654752f));
}

// ---------- K0: zero padded activation buffers + transpose conv weights ----------
#define ZGRAN 1115136
__global__ __launch_bounds__(256) void setup_fill(const float* __restrict__ w0,
                                                  const float* __restrict__ w1,
                                                  const float* __restrict__ w2,
                                                  unsigned short* __restrict__ wb0,
                                                  unsigned short* __restrict__ wb1,
                                                  unsigned short* __restrict__ wb2,
                                                  uint4* __restrict__ zbase) {
    int t = blockIdx.x * 256 + threadIdx.x;
    if (t < ZGRAN) {
        zbase[t] = (uint4){0, 0, 0, 0};
        return;
    }
    int u = t - ZGRAN;
    if (u < 51200) {
        int tap = u >> 11; int r = u & 2047; int n = r >> 6; int k = r & 63;
        wb0[u] = (k < 52) ? f2bf(w0[n * 1300 + k * 25 + tap]) : (unsigned short)0;
    } else if (u < 76800) {
        int v = u - 51200; int tap = v >> 10; int r = v & 1023; int n = r >> 5; int k = r & 31;
        wb1[v] = f2bf(w1[n * 800 + k * 25 + tap]);
    } else if (u < 89600) {
        int v = u - 76800; int tap = v >> 9; int r = v & 511; int n = r >> 5; int k = r & 31;
        wb2[v] = (n < 2) ? f2bf(w2[n * 800 + k * 25 + tap]) : (unsigned short)0;
    }
}

// ---------- K1: fused normalize, 16-lane groups, MLP-batched ----------
// blocks 0..2047: vis -> kn (2 px per 16-lane group, 8 loads in flight)
// blocks 2048..6143: rubin bilinear -> qn (16 loads batched before blend)
__global__ __launch_bounds__(256) void norm_fused(const float* __restrict__ vis,
                                                  const float* __restrict__ rub,
                                                  unsigned short* __restrict__ kn,
                                                  unsigned short* __restrict__ qn) {
    int tid = threadIdx.x;
    int g16 = tid >> 4, l = tid & 15;
    int blk = blockIdx.x;
    if (blk < 2048) {
        int pix0 = blk * 32 + g16 * 2;
        const float* base = vis + (size_t)pix0 * Dd + l * 4;
        float4 v[8];
#pragma unroll
        for (int i = 0; i < 4; i++) v[i] = *(const float4*)(base + i * 64);
#pragma unroll
        for (int i = 0; i < 4; i++) v[4 + i] = *(const float4*)(base + Dd + i * 64);
        float ss0 = 0.f, ss1 = 0.f;
#pragma unroll
        for (int i = 0; i < 4; i++) {
            ss0 += v[i].x * v[i].x + v[i].y * v[i].y + v[i].z * v[i].z + v[i].w * v[i].w;
            ss1 += v[4 + i].x * v[4 + i].x + v[4 + i].y * v[4 + i].y +
                   v[4 + i].z * v[4 + i].z + v[4 + i].w * v[4 + i].w;
        }
#pragma unroll
        for (int o = 1; o <= 8; o <<= 1) {
            ss0 += __shfl_xor(ss0, o, 64);
            ss1 += __shfl_xor(ss1, o, 64);
        }
        float inv0 = __builtin_amdgcn_rsqf(fmaxf(ss0, 1e-24f));
        float inv1 = __builtin_amdgcn_rsqf(fmaxf(ss1, 1e-24f));
        unsigned short* op = kn + (size_t)pix0 * Dd + l * 4;
#pragma unroll
        for (int i = 0; i < 4; i++) {
            ushort4 o4;
            o4.x = f2bf(v[i].x * inv0); o4.y = f2bf(v[i].y * inv0);
            o4.z = f2bf(v[i].z * inv0); o4.w = f2bf(v[i].w * inv0);
            *(ushort4*)(op + i * 64) = o4;
            ushort4 o5;
            o5.x = f2bf(v[4 + i].x * inv1); o5.y = f2bf(v[4 + i].y * inv1);
            o5.z = f2bf(v[4 + i].z * inv1); o5.w = f2bf(v[4 + i].w * inv1);
            *(ushort4*)(op + Dd + i * 64) = o5;
        }
    } else {
        int pix = (blk - 2048) * 16 + g16;
        int b = pix >> 14; int yx = pix & 16383; int y = yx >> 7; int x = yx & 127;
        float sy = 0.5f * y - 0.25f;
        float sx = 0.5f * x - 0.25f;
        int y0 = (int)floorf(sy); float fy = sy - (float)y0;
        int x0 = (int)floorf(sx); float fx = sx - (float)x0;
        int y0c = max(y0, 0), y1c = min(y0 + 1, 63);
        int x0c = max(x0, 0), x1c = min(x0 + 1, 63);
        const float* base = rub + (size_t)b * 4096 * Dd + l * 4;
        const float* p00 = base + (size_t)(y0c * 64 + x0c) * Dd;
        const float* p01 = base + (size_t)(y0c * 64 + x1c) * Dd;
        const float* p10 = base + (size_t)(y1c * 64 + x0c) * Dd;
        const float* p11 = base + (size_t)(y1c * 64 + x1c) * Dd;
        // batch all 16 loads before any arithmetic (MLP)
        float4 A[4], Bv[4], C[4], D[4];
#pragma unroll
        for (int i = 0; i < 4; i++) A[i] = *(const float4*)(p00 + i * 64);
#pragma unroll
        for (int i = 0; i < 4; i++) Bv[i] = *(const float4*)(p01 + i * 64);
#pragma unroll
        for (int i = 0; i < 4; i++) C[i] = *(const float4*)(p10 + i * 64);
#pragma unroll
        for (int i = 0; i < 4; i++) D[i] = *(const float4*)(p11 + i * 64);
        float w00 = (1.f - fy) * (1.f - fx), w01 = (1.f - fy) * fx;
        float w10 = fy * (1.f - fx), w11 = fy * fx;
        float4 bv[4];
        float ss = 0.f;
#pragma unroll
        for (int i = 0; i < 4; i++) {
            float4 v;
            v.x = w00 * A[i].x + w01 * Bv[i].x + w10 * C[i].x + w11 * D[i].x;
            v.y = w00 * A[i].y + w01 * Bv[i].y + w10 * C[i].y + w11 * D[i].y;
            v.z = w00 * A[i].z + w01 * Bv[i].z + w10 * C[i].z + w11 * D[i].z;
            v.w = w00 * A[i].w + w01 * Bv[i].w + w10 * C[i].w + w11 * D[i].w;
            bv[i] = v;
            ss += v.x * v.x + v.y * v.y + v.z * v.z + v.w * v.w;
        }
#pragma unroll
        for (int o = 1; o <= 8; o <<= 1) ss += __shfl_xor(ss, o, 64);
        float inv = __builtin_amdgcn_rsqf(fmaxf(ss, 1e-24f));
        unsigned short* op = qn + (size_t)pix * Dd + l * 4;
#pragma unroll
        for (int i = 0; i < 4; i++) {
            ushort4 o4;
            o4.x = f2bf(bv[i].x * inv); o4.y = f2bf(bv[i].y * inv);
            o4.z = f2bf(bv[i].z * inv); o4.w = f2bf(bv[i].w * inv);
            *(ushort4*)(op + i * 64) = o4;
        }
    }
}

// ---------- K2: 2D-tiled LDS corr + shuffle softmax ----------
__global__ __launch_bounds__(1024) void corr_block(const unsigned short* __restrict__ qn,
                                                   const unsigned short* __restrict__ kn,
                                                   const float* __restrict__ log_temp,
                                                   unsigned short* __restrict__ xb,
                                                   float* __restrict__ out) {
    __shared__ char smem[484 * 5 * 16];
    int tid = threadIdx.x;
    int wid = tid >> 6, lane = tid & 63, l15 = lane & 15, quad = lane >> 4;
    int blk = blockIdx.x;
    int b = blk >> 6, rem = blk & 63;
    int y0 = ((rem >> 3) & 7) << 4, x0 = (rem & 7) << 4;
    int y = y0 + wid;

    const unsigned short* src0; int dst0;
    const unsigned short* src1 = nullptr; int dst1 = 0;
    bool hav1;
    {
        int g = tid;
        int px = g >> 2, sub = g & 3;
        int ry = px / 22, rx = px - ry * 22;
        int yy = min(max(y0 - 3 + ry, 0), 127);
        int xx = min(max(x0 - 3 + rx, 0), 127);
        src0 = kn + ((size_t)(b << 14) + yy * 128 + xx) * 256 + sub * 8;
        dst0 = (px * 5 + sub) * 16;
        g = 1024 + tid;
        hav1 = (g < 1936);
        int gc = hav1 ? g : 1935;
        px = gc >> 2; sub = gc & 3;
        ry = px / 22; rx = px - ry * 22;
        yy = min(max(y0 - 3 + ry, 0), 127);
        xx = min(max(x0 - 3 + rx, 0), 127);
        src1 = kn + ((size_t)(b << 14) + yy * 128 + xx) * 256 + sub * 8;
        dst1 = (px * 5 + sub) * 16;
    }
    int lpixoff[10];
#pragma unroll
    for (int f = 0; f < 10; f++) {
        int p = min(f * 16 + l15, 153);
        int pr = p / 22, pc = p - pr * 22;
        lpixoff[f] = (((wid + pr) * 22 + pc) * 5 + quad) * 16;
    }
    const unsigned short* aptr = qn + ((size_t)(b << 14) + y * 128 + x0 + l15) * 256 + quad * 8;

    f32x4 acc[10];
#pragma unroll
    for (int f = 0; f < 10; f++) acc[f] = (f32x4){0.f, 0.f, 0.f, 0.f};

    uint4 v0 = *(const uint4*)src0;
    uint4 v1 = *(const uint4*)src1;
    s16x8 an = *(const s16x8*)aptr;
    for (int c = 0; c < 8; c++) {
        uint4 w0v = v0, w1v = v1;
        s16x8 a = an;
        if (c < 7) {
            v0 = *(const uint4*)(src0 + (c + 1) * 32);
            v1 = *(const uint4*)(src1 + (c + 1) * 32);
            an = *(const s16x8*)(aptr + (c + 1) * 32);
        }
        __syncthreads();
        *(uint4*)(smem + dst0) = w0v;
        if (hav1) *(uint4*)(smem + dst1) = w1v;
        __syncthreads();
#pragma unroll
        for (int f = 0; f < 10; f++) {
            s16x8 bf = *(const s16x8*)(smem + lpixoff[f]);
            acc[f] = __builtin_amdgcn_mfma_f32_16x16x32_bf16(a, bf, acc[f], 0, 0, 0);
        }
    }

    float inv_temp = expf(-log_temp[0]);
    float vmax[4] = {-1e30f, -1e30f, -1e30f, -1e30f};
#pragma unroll
    for (int f = 0; f < 10; f++) {
        int n = f * 16 + l15;
        if (n <= 153) {
            int dy = n / 22 - 3;
            int rx = n - (dy + 3) * 22;
#pragma unroll
            for (int i = 0; i < 4; i++) {
                int m = quad * 4 + i;
                int dx = rx - m - 3;
                if ((unsigned)(dx + 3) <= 6u) vmax[i] = fmaxf(vmax[i], acc[f][i]);
            }
        }
    }
#pragma unroll
    for (int o = 1; o <= 8; o <<= 1) {
#pragma unroll
        for (int i = 0; i < 4; i++) vmax[i] = fmaxf(vmax[i], __shfl_xor(vmax[i], o, 64));
    }
    float se[4] = {0, 0, 0, 0}, sey[4] = {0, 0, 0, 0}, sex[4] = {0, 0, 0, 0}, emax[4] = {0, 0, 0, 0};
    unsigned short* xrow = xb + ((size_t)(b * WP + y + 2) * WP + x0 + 2) * 64;
#pragma unroll
    for (int f = 0; f < 10; f++) {
        int n = f * 16 + l15;
        if (n <= 153) {
            int dy = n / 22 - 3;
            int rx = n - (dy + 3) * 22;
#pragma unroll
            for (int i = 0; i < 4; i++) {
                int m = quad * 4 + i;
                int dx = rx - m - 3;
                if ((unsigned)(dx + 3) <= 6u) {
                    float v = acc[f][i];
                    float e = expf((v - vmax[i]) * inv_temp);
                    se[i] += e;
                    sey[i] += e * (float)dy;
                    sex[i] += e * (float)dx;
                    emax[i] = fmaxf(emax[i], e);
                    xrow[(size_t)m * 64 + 2 + (dy + 3) * 7 + (dx + 3)] = f2bf(v);
                }
            }
        }
    }
#pragma unroll
    for (int o = 1; o <= 8; o <<= 1) {
#pragma unroll
        for (int i = 0; i < 4; i++) {
            se[i] += __shfl_xor(se[i], o, 64);
            sey[i] += __shfl_xor(sey[i], o, 64);
            sex[i] += __shfl_xor(sex[i], o, 64);
            emax[i] = fmaxf(emax[i], __shfl_xor(emax[i], o, 64));
        }
    }
    if (l15 == 0) {
#pragma unroll
        for (int i = 0; i < 4; i++) {
            int m = quad * 4 + i;
            float inv_se = 1.0f / se[i];
            float dyv = sey[i] * inv_se, dxv = sex[i] * inv_se, conf = emax[i] * inv_se;
            unsigned short* xp = xrow + (size_t)m * 64;
            xp[0] = f2bf(dyv); xp[1] = f2bf(dxv); xp[51] = f2bf(conf);
            float* op = out + (size_t)b * 5 * HW + y * 128 + x0 + m;
            op[2 * HW] = dyv; op[3 * HW] = dxv; op[4 * HW] = conf;
        }
    }
}

// ---------- 16x16-tile MFMA conv: block=1024thr/16 waves, wave = 16px row x OC ----------
template <int KS, int OC, bool GELU>
__global__ __launch_bounds__(1024) void conv_tile(const unsigned short* __restrict__ in,
                                                  const unsigned short* __restrict__ wb,
                                                  const float* __restrict__ bias,
                                                  unsigned short* __restrict__ outp) {
    constexpr int ICP = KS * 32;
    constexpr int NF = OC / 16;
    constexpr int ABYTES = 400 * 5 * 16;        // 32000
    constexpr int WBYTES = 5 * OC * 5 * 16;     // OC*400
    __shared__ char smem[ABYTES + WBYTES];
    int tid = threadIdx.x;
    int wv = tid >> 6, lane = tid & 63, l15 = lane & 15, quad = lane >> 4;
    int blk = blockIdx.x;
    int b = blk >> 6, ty = (blk >> 3) & 7, tx = blk & 7;
    int y0 = ty * 16, x0 = tx * 16;

    f32x4 acc[NF];
#pragma unroll
    for (int g = 0; g < NF; g++) acc[g] = (f32x4){0.f, 0.f, 0.f, 0.f};

    for (int ks = 0; ks < KS; ks++) {
        __syncthreads();           // prior chunk's compute done
#pragma unroll
        for (int i = 0; i < 2; i++) {
            int g = i * 1024 + tid;
            if (g < 1600) {
                int px = g >> 2, sub = g & 3;
                int r = px / 20, c = px - r * 20;
                *(uint4*)(smem + (px * 5 + sub) * 16) =
                    *(const uint4*)(in + ((size_t)(b * WP + y0 + r) * WP + x0 + c) * ICP + ks * 32 + sub * 8);
            }
        }
        for (int ky = 0; ky < 5; ky++) {
            if (ky > 0) __syncthreads();    // prior compute done (W region free)
            constexpr int WGR = 5 * OC * 4;
#pragma unroll
            for (int i = 0; i < (WGR + 1023) / 1024; i++) {
                int g = i * 1024 + tid;
                if (g < WGR) {
                    int nl = g >> 2, sub = g & 3;
                    *(uint4*)(smem + ABYTES + (nl * 5 + sub) * 16) =
                        *(const uint4*)(wb + ((size_t)(ky * 5 * OC) + nl) * ICP + ks * 32 + sub * 8);
                }
            }
            __syncthreads();
#pragma unroll
            for (int kx = 0; kx < 5; kx++) {
                int abyte = (((wv + ky) * 20 + l15 + kx) * 5 + quad) * 16;
                s16x8 a = *(const s16x8*)(smem + abyte);
#pragma unroll
                for (int g = 0; g < NF; g++) {
                    int wbyte = ABYTES + ((kx * OC + g * 16 + l15) * 5 + quad) * 16;
                    s16x8 bf = *(const s16x8*)(smem + wbyte);
                    acc[g] = __builtin_amdgcn_mfma_f32_16x16x32_bf16(a, bf, acc[g], 0, 0, 0);
                }
            }
        }
    }
    size_t orow = ((size_t)(b * WP + y0 + wv + 2) * WP + x0 + 2) * OC;
#pragma unroll
    for (int g = 0; g < NF; g++) {
        float bv = bias[g * 16 + l15];
#pragma unroll
        for (int r = 0; r < 4; r++) {
            int m = quad * 4 + r;
            float v = acc[g][r] + bv;
            if (GELU) v = gelu_exact(v);
            outp[orow + (size_t)m * OC + g * 16 + l15] = f2bf(v);
        }
    }
}

// ---------- final conv (32->2, OC padded 16), tile version + residual + sky scaling ----------
__global__ __launch_bounds__(1024) void conv_final_tile(const unsigned short* __restrict__ in,
                                                        const unsigned short* __restrict__ wb,
                                                        const float* __restrict__ bias,
                                                        float* __restrict__ out) {
    constexpr int ICP = 32, OC = 16;
    constexpr int ABYTES = 400 * 5 * 16;
    constexpr int WBYTES = 5 * OC * 5 * 16;   // 6400
    __shared__ char smem[ABYTES + WBYTES];
    int tid = threadIdx.x;
    int wv = tid >> 6, lane = tid & 63, l15 = lane & 15, quad = lane >> 4;
    int blk = blockIdx.x;
    int b = blk >> 6, ty = (blk >> 3) & 7, tx = blk & 7;
    int y0 = ty * 16, x0 = tx * 16;

    f32x4 acc = (f32x4){0.f, 0.f, 0.f, 0.f};
    __syncthreads();
#pragma unroll
    for (int i = 0; i < 2; i++) {
        int g = i * 1024 + tid;
        if (g < 1600) {
            int px = g >> 2, sub = g & 3;
            int r = px / 20, c = px - r * 20;
            *(uint4*)(smem + (px * 5 + sub) * 16) =
                *(const uint4*)(in + ((size_t)(b * WP + y0 + r) * WP + x0 + c) * ICP + sub * 8);
        }
    }
    for (int ky = 0; ky < 5; ky++) {
        if (ky > 0) __syncthreads();
        constexpr int WGR = 5 * OC * 4;   // 320
        {
            int g = tid;
            if (g < WGR) {
                int nl = g >> 2, sub = g & 3;
                *(uint4*)(smem + ABYTES + (nl * 5 + sub) * 16) =
                    *(const uint4*)(wb + ((size_t)(ky * 5 * OC) + nl) * ICP + sub * 8);
            }
        }
        __syncthreads();
#pragma unroll
        for (int kx = 0; kx < 5; kx++) {
            int abyte = (((wv + ky) * 20 + l15 + kx) * 5 + quad) * 16;
            s16x8 a = *(const s16x8*)(smem + abyte);
            int wbyte = ABYTES + ((kx * OC + l15) * 5 + quad) * 16;
            s16x8 bf = *(const s16x8*)(smem + wbyte);
            acc = __builtin_amdgcn_mfma_f32_16x16x32_bf16(a, bf, acc, 0, 0, 0);
        }
    }
    if (l15 < 2) {
        float bv = bias[l15];
#pragma unroll
        for (int r = 0; r < 4; r++) {
            int m = quad * 4 + r;
            size_t p5 = (size_t)b * 5 * HW + (y0 + wv) * Ww + x0 + m;
            float a = acc[r] + bv;
            if (l15 == 0) {
                float dyv = out[p5 + 2 * HW];
                out[p5 + HW] = (dyv + a) * 1.6f;   // ddec
            } else {
                float dxv = out[p5 + 3 * HW];
                out[p5] = (dxv + a) * 1.6f;        // dra
            }
        }
    }
}

extern "C" void kernel_launch(void* const* d_in, const int* in_sizes, int n_in,
                              void* d_out, int out_size, void* d_ws, size_t ws_size,
                              hipStream_t stream) {
    const float* rub = (const float*)d_in[0];
    const float* vis = (const float*)d_in[1];
    const float* w0 = (const float*)d_in[2];
    const float* b0 = (const float*)d_in[3];
    const float* w1 = (const float*)d_in[4];
    const float* b1 = (const float*)d_in[5];
    const float* w2 = (const float*)d_in[6];
    const float* b2 = (const float*)d_in[7];
    const float* log_temp = (const float*)d_in[8];
    float* out = (float*)d_out;

    char* ws = (char*)d_ws;
    size_t off = 0;
    const size_t PADPIX = (size_t)Bb * WP * WP;     // 69,696
    unsigned short* kn = (unsigned short*)(ws + off); off += (size_t)NPIX * Dd * 2;
    unsigned short* qn = (unsigned short*)(ws + off); off += (size_t)NPIX * Dd * 2;
    unsigned short* xbp = (unsigned short*)(ws + off); off += PADPIX * 64 * 2;   // contiguous
    unsigned short* h1p = (unsigned short*)(ws + off); off += PADPIX * 32 * 2;   //  zero
    unsigned short* h2p = (unsigned short*)(ws + off); off += PADPIX * 32 * 2;   //  region
    unsigned short* wb0 = (unsigned short*)(ws + off); off += 51200 * 2;
    unsigned short* wb1 = (unsigned short*)(ws + off); off += 25600 * 2;
    unsigned short* wb2 = (unsigned short*)(ws + off); off += 12800 * 2;

    setup_fill<<<4706, 256, 0, stream>>>(w0, w1, w2, wb0, wb1, wb2, (uint4*)xbp);
    norm_fused<<<6144, 256, 0, stream>>>(vis, rub, kn, qn);
    corr_block<<<256, 1024, 0, stream>>>(qn, kn, log_temp, xbp, out);
    conv_tile<2, 32, true><<<256, 1024, 0, stream>>>(xbp, wb0, b0, h1p);
    conv_tile<1, 32, true><<<256, 1024, 0, stream>>>(h1p, wb1, b1, h2p);
    conv_final_tile<<<256, 1024, 0, stream>>>(h2p, wb2, b2, out);
}

// Round 3
// 206.598 us; speedup vs baseline: 1.2012x; 1.0441x over previous
//
#include <hip/hip_runtime.h>
#include <math.h>

#define Hh 128
#define Ww 128
#define Dd 256
#define Bb 4
#define HW (Hh*Ww)        // 16384
#define NPIX (Bb*HW)      // 65536
#define WP 132            // padded width/height (2-px zero ring)

typedef __attribute__((ext_vector_type(8))) short s16x8;   // 8 bf16 (4 VGPRs)
typedef __attribute__((ext_vector_type(4))) float f32x4;

__device__ __forceinline__ unsigned short f2bf(float f) {
    unsigned u = __float_as_uint(f);
    u += 0x7FFF + ((u >> 16) & 1);
    return (unsigned short)(u >> 16);
}

__device__ __forceinline__ float gelu_exact(float v) {
    return 0.5f * v * (1.0f + erff(v * 0.70710678118654752f));
}

// ---------- K0: zero padded activation buffers + transpose conv weights ----------
#define ZGRAN 1115136
__global__ __launch_bounds__(256) void setup_fill(const float* __restrict__ w0,
                                                  const float* __restrict__ w1,
                                                  const float* __restrict__ w2,
                                                  unsigned short* __restrict__ wb0,
                                                  unsigned short* __restrict__ wb1,
                                                  unsigned short* __restrict__ wb2,
                                                  uint4* __restrict__ zbase) {
    int t = blockIdx.x * 256 + threadIdx.x;
    if (t < ZGRAN) {
        zbase[t] = (uint4){0, 0, 0, 0};
        return;
    }
    int u = t - ZGRAN;
    if (u < 51200) {
        int tap = u >> 11; int r = u & 2047; int n = r >> 6; int k = r & 63;
        wb0[u] = (k < 52) ? f2bf(w0[n * 1300 + k * 25 + tap]) : (unsigned short)0;
    } else if (u < 76800) {
        int v = u - 51200; int tap = v >> 10; int r = v & 1023; int n = r >> 5; int k = r & 31;
        wb1[v] = f2bf(w1[n * 800 + k * 25 + tap]);
    } else if (u < 89600) {
        int v = u - 76800; int tap = v >> 9; int r = v & 511; int n = r >> 5; int k = r & 31;
        wb2[v] = (n < 2) ? f2bf(w2[n * 800 + k * 25 + tap]) : (unsigned short)0;
    }
}

// ---------- K1: fused normalize ----------
// blocks 0..4095: vis -> kn (16-lane group = 1 px, 4 float4 loads)
// blocks 4096..5119: rubin bilinear -> qn via LDS-staged 6x6 token tile per 8x8 out px
__global__ __launch_bounds__(256) void norm_fused(const float* __restrict__ vis,
                                                  const float* __restrict__ rub,
                                                  unsigned short* __restrict__ kn,
                                                  unsigned short* __restrict__ qn) {
    __shared__ float stok[36 * 260];   // 36 tokens, 260-float stride (bank stagger)
    int tid = threadIdx.x;
    int g16 = tid >> 4, l = tid & 15;
    int blk = blockIdx.x;
    if (blk < 4096) {
        int pix = blk * 16 + g16;
        const float* base = vis + (size_t)pix * Dd + l * 4;
        float4 v[4];
#pragma unroll
        for (int i = 0; i < 4; i++) v[i] = *(const float4*)(base + i * 64);
        float ss = 0.f;
#pragma unroll
        for (int i = 0; i < 4; i++)
            ss += v[i].x * v[i].x + v[i].y * v[i].y + v[i].z * v[i].z + v[i].w * v[i].w;
#pragma unroll
        for (int o = 1; o <= 8; o <<= 1) ss += __shfl_xor(ss, o, 64);
        float inv = __builtin_amdgcn_rsqf(fmaxf(ss, 1e-24f));
        unsigned short* op = kn + (size_t)pix * Dd + l * 4;
#pragma unroll
        for (int i = 0; i < 4; i++) {
            ushort4 o4;
            o4.x = f2bf(v[i].x * inv); o4.y = f2bf(v[i].y * inv);
            o4.z = f2bf(v[i].z * inv); o4.w = f2bf(v[i].w * inv);
            *(ushort4*)(op + i * 64) = o4;
        }
    } else {
        int blk2 = blk - 4096;               // 1024 tiles of 8x8 output px
        int b = blk2 >> 8;
        int rem = blk2 & 255;
        int ty = rem >> 4, tx = rem & 15;
        int oy0 = ty * 8, ox0 = tx * 8;
        int rb = ty * 4 - 1, cb = tx * 4 - 1;    // token window base (6x6)
        // stage 36 tokens x 1KB, coalesced, edge-clamped
#pragma unroll
        for (int i = 0; i < 9; i++) {
            int g = i * 256 + tid;               // 2304 granules exactly
            int t = g >> 6, c = g & 63;
            int jy = t / 6, jx = t - jy * 6;
            int gy = min(max(rb + jy, 0), 63);
            int gx = min(max(cb + jx, 0), 63);
            *(float4*)&stok[t * 260 + c * 4] =
                *(const float4*)(rub + ((size_t)(b * 4096 + gy * 64 + gx)) * 256 + c * 4);
        }
        __syncthreads();
        // each 16-lane group: 4 output px
        for (int k = 0; k < 4; k++) {
            int pp = g16 * 4 + k;
            int r = pp >> 3, c2 = pp & 7;
            int yo = oy0 + r, xo = ox0 + c2;
            float sy = 0.5f * yo - 0.25f, sx = 0.5f * xo - 0.25f;
            float fyf = floorf(sy), fxf = floorf(sx);
            float fy = sy - fyf, fx = sx - fxf;
            int jy0 = (int)fyf - rb, jx0 = (int)fxf - cb;   // in [0,4]
            const float* t00 = &stok[(jy0 * 6 + jx0) * 260 + l * 4];
            const float* t01 = t00 + 260;
            const float* t10 = t00 + 6 * 260;
            const float* t11 = t10 + 260;
            float w00 = (1.f - fy) * (1.f - fx), w01 = (1.f - fy) * fx;
            float w10 = fy * (1.f - fx), w11 = fy * fx;
            float4 bv[4];
            float ss = 0.f;
#pragma unroll
            for (int i = 0; i < 4; i++) {
                float4 a = *(const float4*)(t00 + i * 64);
                float4 b1 = *(const float4*)(t01 + i * 64);
                float4 c = *(const float4*)(t10 + i * 64);
                float4 d = *(const float4*)(t11 + i * 64);
                float4 v;
                v.x = w00 * a.x + w01 * b1.x + w10 * c.x + w11 * d.x;
                v.y = w00 * a.y + w01 * b1.y + w10 * c.y + w11 * d.y;
                v.z = w00 * a.z + w01 * b1.z + w10 * c.z + w11 * d.z;
                v.w = w00 * a.w + w01 * b1.w + w10 * c.w + w11 * d.w;
                bv[i] = v;
                ss += v.x * v.x + v.y * v.y + v.z * v.z + v.w * v.w;
            }
#pragma unroll
            for (int o = 1; o <= 8; o <<= 1) ss += __shfl_xor(ss, o, 64);
            float inv = __builtin_amdgcn_rsqf(fmaxf(ss, 1e-24f));
            size_t pix = (size_t)(b << 14) + yo * 128 + xo;
            unsigned short* op = qn + pix * Dd + l * 4;
#pragma unroll
            for (int i = 0; i < 4; i++) {
                ushort4 o4;
                o4.x = f2bf(bv[i].x * inv); o4.y = f2bf(bv[i].y * inv);
                o4.z = f2bf(bv[i].z * inv); o4.w = f2bf(bv[i].w * inv);
                *(ushort4*)(op + i * 64) = o4;
            }
        }
    }
}

// ---------- K2: 2D-tiled LDS corr + shuffle softmax (16x8 tiles, 2 blocks/CU) ----------
__global__ __launch_bounds__(512, 4) void corr_block(const unsigned short* __restrict__ qn,
                                                     const unsigned short* __restrict__ kn,
                                                     const float* __restrict__ log_temp,
                                                     unsigned short* __restrict__ xb,
                                                     float* __restrict__ out) {
    __shared__ char smem[308 * 5 * 16];      // 24640 B (14x22 halo)
    int tid = threadIdx.x;
    int wid = tid >> 6, lane = tid & 63, l15 = lane & 15, quad = lane >> 4;
    int blk = blockIdx.x;                    // 512 = 4 b x 16 ty x 8 tx
    int b = blk >> 7, rem = blk & 127;
    int y0 = (rem >> 3) << 3, x0 = (rem & 7) << 4;
    int y = y0 + wid;

    // staging: 308 px x 4 granules = 1232, 3 rounds of 512
    const unsigned short* src0; int dst0;
    const unsigned short* src1; int dst1;
    const unsigned short* src2; int dst2; bool hav2;
    {
        int g = tid;
        int px = g >> 2, sub = g & 3;
        int ry = px / 22, rx = px - ry * 22;
        int yy = min(max(y0 - 3 + ry, 0), 127);
        int xx = min(max(x0 - 3 + rx, 0), 127);
        src0 = kn + ((size_t)(b << 14) + yy * 128 + xx) * 256 + sub * 8;
        dst0 = (px * 5 + sub) * 16;
        g = 512 + tid;
        px = g >> 2; sub = g & 3;
        ry = px / 22; rx = px - ry * 22;
        yy = min(max(y0 - 3 + ry, 0), 127);
        xx = min(max(x0 - 3 + rx, 0), 127);
        src1 = kn + ((size_t)(b << 14) + yy * 128 + xx) * 256 + sub * 8;
        dst1 = (px * 5 + sub) * 16;
        g = 1024 + tid;
        hav2 = (g < 1232);
        int gc = hav2 ? g : 1231;
        px = gc >> 2; sub = gc & 3;
        ry = px / 22; rx = px - ry * 22;
        yy = min(max(y0 - 3 + ry, 0), 127);
        xx = min(max(x0 - 3 + rx, 0), 127);
        src2 = kn + ((size_t)(b << 14) + yy * 128 + xx) * 256 + sub * 8;
        dst2 = (px * 5 + sub) * 16;
    }
    int lpixoff[10];
#pragma unroll
    for (int f = 0; f < 10; f++) {
        int p = min(f * 16 + l15, 153);
        int pr = p / 22, pc = p - pr * 22;
        lpixoff[f] = (((wid + pr) * 22 + pc) * 5 + quad) * 16;
    }
    const unsigned short* aptr = qn + ((size_t)(b << 14) + y * 128 + x0 + l15) * 256 + quad * 8;

    f32x4 acc[10];
#pragma unroll
    for (int f = 0; f < 10; f++) acc[f] = (f32x4){0.f, 0.f, 0.f, 0.f};

    uint4 v0 = *(const uint4*)src0;
    uint4 v1 = *(const uint4*)src1;
    uint4 v2 = *(const uint4*)src2;
    s16x8 an = *(const s16x8*)aptr;
    for (int c = 0; c < 8; c++) {
        uint4 w0v = v0, w1v = v1, w2v = v2;
        s16x8 a = an;
        if (c < 7) {
            v0 = *(const uint4*)(src0 + (c + 1) * 32);
            v1 = *(const uint4*)(src1 + (c + 1) * 32);
            v2 = *(const uint4*)(src2 + (c + 1) * 32);
            an = *(const s16x8*)(aptr + (c + 1) * 32);
        }
        __syncthreads();
        *(uint4*)(smem + dst0) = w0v;
        *(uint4*)(smem + dst1) = w1v;
        if (hav2) *(uint4*)(smem + dst2) = w2v;
        __syncthreads();
#pragma unroll
        for (int f = 0; f < 10; f++) {
            s16x8 bf = *(const s16x8*)(smem + lpixoff[f]);
            acc[f] = __builtin_amdgcn_mfma_f32_16x16x32_bf16(a, bf, acc[f], 0, 0, 0);
        }
    }

    float inv_temp = expf(-log_temp[0]);
    float vmax[4] = {-1e30f, -1e30f, -1e30f, -1e30f};
#pragma unroll
    for (int f = 0; f < 10; f++) {
        int n = f * 16 + l15;
        if (n <= 153) {
            int dy = n / 22 - 3;
            int rx = n - (dy + 3) * 22;
#pragma unroll
            for (int i = 0; i < 4; i++) {
                int m = quad * 4 + i;
                int dx = rx - m - 3;
                if ((unsigned)(dx + 3) <= 6u) vmax[i] = fmaxf(vmax[i], acc[f][i]);
            }
        }
    }
#pragma unroll
    for (int o = 1; o <= 8; o <<= 1) {
#pragma unroll
        for (int i = 0; i < 4; i++) vmax[i] = fmaxf(vmax[i], __shfl_xor(vmax[i], o, 64));
    }
    float se[4] = {0, 0, 0, 0}, sey[4] = {0, 0, 0, 0}, sex[4] = {0, 0, 0, 0}, emax[4] = {0, 0, 0, 0};
    unsigned short* xrow = xb + ((size_t)(b * WP + y + 2) * WP + x0 + 2) * 64;
#pragma unroll
    for (int f = 0; f < 10; f++) {
        int n = f * 16 + l15;
        if (n <= 153) {
            int dy = n / 22 - 3;
            int rx = n - (dy + 3) * 22;
#pragma unroll
            for (int i = 0; i < 4; i++) {
                int m = quad * 4 + i;
                int dx = rx - m - 3;
                if ((unsigned)(dx + 3) <= 6u) {
                    float v = acc[f][i];
                    float e = expf((v - vmax[i]) * inv_temp);
                    se[i] += e;
                    sey[i] += e * (float)dy;
                    sex[i] += e * (float)dx;
                    emax[i] = fmaxf(emax[i], e);
                    xrow[(size_t)m * 64 + 2 + (dy + 3) * 7 + (dx + 3)] = f2bf(v);
                }
            }
        }
    }
#pragma unroll
    for (int o = 1; o <= 8; o <<= 1) {
#pragma unroll
        for (int i = 0; i < 4; i++) {
            se[i] += __shfl_xor(se[i], o, 64);
            sey[i] += __shfl_xor(sey[i], o, 64);
            sex[i] += __shfl_xor(sex[i], o, 64);
            emax[i] = fmaxf(emax[i], __shfl_xor(emax[i], o, 64));
        }
    }
    if (l15 == 0) {
#pragma unroll
        for (int i = 0; i < 4; i++) {
            int m = quad * 4 + i;
            float inv_se = 1.0f / se[i];
            float dyv = sey[i] * inv_se, dxv = sex[i] * inv_se, conf = emax[i] * inv_se;
            unsigned short* xp = xrow + (size_t)m * 64;
            xp[0] = f2bf(dyv); xp[1] = f2bf(dxv); xp[51] = f2bf(conf);
            float* op = out + (size_t)b * 5 * HW + y * 128 + x0 + m;
            op[2 * HW] = dyv; op[3 * HW] = dxv; op[4 * HW] = conf;
        }
    }
}

// ---------- 16x8-tile MFMA conv: 512 thr / 8 waves, wave = 1 out row; 2 blocks/CU ----------
template <int KS, int OC, bool GELU>
__global__ __launch_bounds__(512, 4) void conv_tile(const unsigned short* __restrict__ in,
                                                    const unsigned short* __restrict__ wb,
                                                    const float* __restrict__ bias,
                                                    unsigned short* __restrict__ outp) {
    constexpr int ICP = KS * 32;
    constexpr int NF = OC / 16;
    constexpr int ABYTES = 240 * 5 * 16;        // 12x20 halo = 19200
    constexpr int WBYTES = 5 * OC * 5 * 16;
    __shared__ char smem[ABYTES + WBYTES];
    int tid = threadIdx.x;
    int wv = tid >> 6, lane = tid & 63, l15 = lane & 15, quad = lane >> 4;
    int blk = blockIdx.x;                       // 512 = 4 b x 16 ty x 8 tx
    int b = blk >> 7, rem = blk & 127;
    int ty = rem >> 3, tx = rem & 7;
    int y0 = ty * 8, x0 = tx * 16;

    f32x4 acc[NF];
#pragma unroll
    for (int g = 0; g < NF; g++) acc[g] = (f32x4){0.f, 0.f, 0.f, 0.f};

    for (int ks = 0; ks < KS; ks++) {
        __syncthreads();           // prior chunk's compute done
#pragma unroll
        for (int i = 0; i < 2; i++) {
            int g = i * 512 + tid;
            if (g < 960) {
                int px = g >> 2, sub = g & 3;
                int r = px / 20, c = px - r * 20;
                *(uint4*)(smem + (px * 5 + sub) * 16) =
                    *(const uint4*)(in + ((size_t)(b * WP + y0 + r) * WP + x0 + c) * ICP + ks * 32 + sub * 8);
            }
        }
        for (int ky = 0; ky < 5; ky++) {
            if (ky > 0) __syncthreads();    // prior compute done (W region free)
            constexpr int WGR = 5 * OC * 4;
#pragma unroll
            for (int i = 0; i < (WGR + 511) / 512; i++) {
                int g = i * 512 + tid;
                if (g < WGR) {
                    int nl = g >> 2, sub = g & 3;
                    *(uint4*)(smem + ABYTES + (nl * 5 + sub) * 16) =
                        *(const uint4*)(wb + ((size_t)(ky * 5 * OC) + nl) * ICP + ks * 32 + sub * 8);
                }
            }
            __syncthreads();
#pragma unroll
            for (int kx = 0; kx < 5; kx++) {
                int abyte = (((wv + ky) * 20 + l15 + kx) * 5 + quad) * 16;
                s16x8 a = *(const s16x8*)(smem + abyte);
#pragma unroll
                for (int g = 0; g < NF; g++) {
                    int wbyte = ABYTES + ((kx * OC + g * 16 + l15) * 5 + quad) * 16;
                    s16x8 bf = *(const s16x8*)(smem + wbyte);
                    acc[g] = __builtin_amdgcn_mfma_f32_16x16x32_bf16(a, bf, acc[g], 0, 0, 0);
                }
            }
        }
    }
    size_t orow = ((size_t)(b * WP + y0 + wv + 2) * WP + x0 + 2) * OC;
#pragma unroll
    for (int g = 0; g < NF; g++) {
        float bv = bias[g * 16 + l15];
#pragma unroll
        for (int r = 0; r < 4; r++) {
            int m = quad * 4 + r;
            float v = acc[g][r] + bv;
            if (GELU) v = gelu_exact(v);
            outp[orow + (size_t)m * OC + g * 16 + l15] = f2bf(v);
        }
    }
}

// ---------- final conv (32->2, OC padded 16), 16x8 tiles + residual + sky scaling ----------
__global__ __launch_bounds__(512, 4) void conv_final_tile(const unsigned short* __restrict__ in,
                                                          const unsigned short* __restrict__ wb,
                                                          const float* __restrict__ bias,
                                                          float* __restrict__ out) {
    constexpr int ICP = 32, OC = 16;
    constexpr int ABYTES = 240 * 5 * 16;
    constexpr int WBYTES = 5 * OC * 5 * 16;   // 6400
    __shared__ char smem[ABYTES + WBYTES];
    int tid = threadIdx.x;
    int wv = tid >> 6, lane = tid & 63, l15 = lane & 15, quad = lane >> 4;
    int blk = blockIdx.x;
    int b = blk >> 7, rem = blk & 127;
    int ty = rem >> 3, tx = rem & 7;
    int y0 = ty * 8, x0 = tx * 16;

    f32x4 acc = (f32x4){0.f, 0.f, 0.f, 0.f};
#pragma unroll
    for (int i = 0; i < 2; i++) {
        int g = i * 512 + tid;
        if (g < 960) {
            int px = g >> 2, sub = g & 3;
            int r = px / 20, c = px - r * 20;
            *(uint4*)(smem + (px * 5 + sub) * 16) =
                *(const uint4*)(in + ((size_t)(b * WP + y0 + r) * WP + x0 + c) * ICP + sub * 8);
        }
    }
    for (int ky = 0; ky < 5; ky++) {
        if (ky > 0) __syncthreads();
        constexpr int WGR = 5 * OC * 4;   // 320
        {
            int g = tid;
            if (g < WGR) {
                int nl = g >> 2, sub = g & 3;
                *(uint4*)(smem + ABYTES + (nl * 5 + sub) * 16) =
                    *(const uint4*)(wb + ((size_t)(ky * 5 * OC) + nl) * ICP + sub * 8);
            }
        }
        __syncthreads();
#pragma unroll
        for (int kx = 0; kx < 5; kx++) {
            int abyte = (((wv + ky) * 20 + l15 + kx) * 5 + quad) * 16;
            s16x8 a = *(const s16x8*)(smem + abyte);
            int wbyte = ABYTES + ((kx * OC + l15) * 5 + quad) * 16;
            s16x8 bf = *(const s16x8*)(smem + wbyte);
            acc = __builtin_amdgcn_mfma_f32_16x16x32_bf16(a, bf, acc, 0, 0, 0);
        }
    }
    if (l15 < 2) {
        float bv = bias[l15];
#pragma unroll
        for (int r = 0; r < 4; r++) {
            int m = quad * 4 + r;
            size_t p5 = (size_t)b * 5 * HW + (y0 + wv) * Ww + x0 + m;
            float a = acc[r] + bv;
            if (l15 == 0) {
                float dyv = out[p5 + 2 * HW];
                out[p5 + HW] = (dyv + a) * 1.6f;   // ddec
            } else {
                float dxv = out[p5 + 3 * HW];
                out[p5] = (dxv + a) * 1.6f;        // dra
            }
        }
    }
}

extern "C" void kernel_launch(void* const* d_in, const int* in_sizes, int n_in,
                              void* d_out, int out_size, void* d_ws, size_t ws_size,
                              hipStream_t stream) {
    const float* rub = (const float*)d_in[0];
    const float* vis = (const float*)d_in[1];
    const float* w0 = (const float*)d_in[2];
    const float* b0 = (const float*)d_in[3];
    const float* w1 = (const float*)d_in[4];
    const float* b1 = (const float*)d_in[5];
    const float* w2 = (const float*)d_in[6];
    const float* b2 = (const float*)d_in[7];
    const float* log_temp = (const float*)d_in[8];
    float* out = (float*)d_out;

    char* ws = (char*)d_ws;
    size_t off = 0;
    const size_t PADPIX = (size_t)Bb * WP * WP;     // 69,696
    unsigned short* kn = (unsigned short*)(ws + off); off += (size_t)NPIX * Dd * 2;
    unsigned short* qn = (unsigned short*)(ws + off); off += (size_t)NPIX * Dd * 2;
    unsigned short* xbp = (unsigned short*)(ws + off); off += PADPIX * 64 * 2;   // contiguous
    unsigned short* h1p = (unsigned short*)(ws + off); off += PADPIX * 32 * 2;   //  zero
    unsigned short* h2p = (unsigned short*)(ws + off); off += PADPIX * 32 * 2;   //  region
    unsigned short* wb0 = (unsigned short*)(ws + off); off += 51200 * 2;
    unsigned short* wb1 = (unsigned short*)(ws + off); off += 25600 * 2;
    unsigned short* wb2 = (unsigned short*)(ws + off); off += 12800 * 2;

    setup_fill<<<4706, 256, 0, stream>>>(w0, w1, w2, wb0, wb1, wb2, (uint4*)xbp);
    norm_fused<<<5120, 256, 0, stream>>>(vis, rub, kn, qn);
    corr_block<<<512, 512, 0, stream>>>(qn, kn, log_temp, xbp, out);
    conv_tile<2, 32, true><<<512, 512, 0, stream>>>(xbp, wb0, b0, h1p);
    conv_tile<1, 32, true><<<512, 512, 0, stream>>>(h1p, wb1, b1, h2p);
    conv_final_tile<<<512, 512, 0, stream>>>(h2p, wb2, b2, out);
}

// Round 4
// 195.748 us; speedup vs baseline: 1.2678x; 1.0554x over previous
//
#include <hip/hip_runtime.h>
#include <math.h>

#define Hh 128
#define Ww 128
#define Dd 256
#define Bb 4
#define HW (Hh*Ww)        // 16384
#define NPIX (Bb*HW)      // 65536
#define WP 132            // padded width/height (2-px zero ring)

typedef __attribute__((ext_vector_type(8))) short s16x8;   // 8 bf16 (4 VGPRs)
typedef __attribute__((ext_vector_type(4))) float f32x4;

__device__ __forceinline__ unsigned short f2bf(float f) {
    unsigned u = __float_as_uint(f);
    u += 0x7FFF + ((u >> 16) & 1);
    return (unsigned short)(u >> 16);
}

__device__ __forceinline__ float gelu_exact(float v) {
    return 0.5f * v * (1.0f + erff(v * 0.70710678118654752f));
}

// ---------- K0: merged setup (zero pads + weight transpose) and normalize ----------
// blocks 0..4705: zero fill + weight transpose
// blocks 4706..8801: vis -> kn
// blocks 8802..9825: rubin bilinear -> qn via LDS-staged 6x6 token tile
#define ZGRAN 1115136
__global__ __launch_bounds__(256) void setup_norm(const float* __restrict__ w0,
                                                  const float* __restrict__ w1,
                                                  const float* __restrict__ w2,
                                                  unsigned short* __restrict__ wb0,
                                                  unsigned short* __restrict__ wb1,
                                                  unsigned short* __restrict__ wb2,
                                                  uint4* __restrict__ zbase,
                                                  const float* __restrict__ vis,
                                                  const float* __restrict__ rub,
                                                  unsigned short* __restrict__ kn,
                                                  unsigned short* __restrict__ qn) {
    __shared__ float stok[36 * 260];
    int tid = threadIdx.x;
    int blk = blockIdx.x;
    if (blk < 4706) {
        int t = blk * 256 + tid;
        if (t < ZGRAN) {
            zbase[t] = (uint4){0, 0, 0, 0};
            return;
        }
        int u = t - ZGRAN;
        if (u < 51200) {
            int tap = u >> 11; int r = u & 2047; int n = r >> 6; int k = r & 63;
            wb0[u] = (k < 52) ? f2bf(w0[n * 1300 + k * 25 + tap]) : (unsigned short)0;
        } else if (u < 76800) {
            int v = u - 51200; int tap = v >> 10; int r = v & 1023; int n = r >> 5; int k = r & 31;
            wb1[v] = f2bf(w1[n * 800 + k * 25 + tap]);
        } else if (u < 89600) {
            int v = u - 76800; int tap = v >> 9; int r = v & 511; int n = r >> 5; int k = r & 31;
            wb2[v] = (n < 2) ? f2bf(w2[n * 800 + k * 25 + tap]) : (unsigned short)0;
        }
        return;
    }
    int nb = blk - 4706;
    int g16 = tid >> 4, l = tid & 15;
    if (nb < 4096) {
        int pix = nb * 16 + g16;
        const float* base = vis + (size_t)pix * Dd + l * 4;
        float4 v[4];
#pragma unroll
        for (int i = 0; i < 4; i++) v[i] = *(const float4*)(base + i * 64);
        float ss = 0.f;
#pragma unroll
        for (int i = 0; i < 4; i++)
            ss += v[i].x * v[i].x + v[i].y * v[i].y + v[i].z * v[i].z + v[i].w * v[i].w;
#pragma unroll
        for (int o = 1; o <= 8; o <<= 1) ss += __shfl_xor(ss, o, 64);
        float inv = __builtin_amdgcn_rsqf(fmaxf(ss, 1e-24f));
        unsigned short* op = kn + (size_t)pix * Dd + l * 4;
#pragma unroll
        for (int i = 0; i < 4; i++) {
            ushort4 o4;
            o4.x = f2bf(v[i].x * inv); o4.y = f2bf(v[i].y * inv);
            o4.z = f2bf(v[i].z * inv); o4.w = f2bf(v[i].w * inv);
            *(ushort4*)(op + i * 64) = o4;
        }
    } else {
        int blk2 = nb - 4096;                // 1024 tiles of 8x8 output px
        int b = blk2 >> 8;
        int rem = blk2 & 255;
        int ty = rem >> 4, tx = rem & 15;
        int oy0 = ty * 8, ox0 = tx * 8;
        int rb = ty * 4 - 1, cb = tx * 4 - 1;    // token window base (6x6)
#pragma unroll
        for (int i = 0; i < 9; i++) {
            int g = i * 256 + tid;               // 2304 granules exactly
            int t = g >> 6, c = g & 63;
            int jy = t / 6, jx = t - jy * 6;
            int gy = min(max(rb + jy, 0), 63);
            int gx = min(max(cb + jx, 0), 63);
            *(float4*)&stok[t * 260 + c * 4] =
                *(const float4*)(rub + ((size_t)(b * 4096 + gy * 64 + gx)) * 256 + c * 4);
        }
        __syncthreads();
        for (int k = 0; k < 4; k++) {
            int pp = g16 * 4 + k;
            int r = pp >> 3, c2 = pp & 7;
            int yo = oy0 + r, xo = ox0 + c2;
            float sy = 0.5f * yo - 0.25f, sx = 0.5f * xo - 0.25f;
            float fyf = floorf(sy), fxf = floorf(sx);
            float fy = sy - fyf, fx = sx - fxf;
            int jy0 = (int)fyf - rb, jx0 = (int)fxf - cb;   // in [0,4]
            const float* t00 = &stok[(jy0 * 6 + jx0) * 260 + l * 4];
            const float* t01 = t00 + 260;
            const float* t10 = t00 + 6 * 260;
            const float* t11 = t10 + 260;
            float w00 = (1.f - fy) * (1.f - fx), w01 = (1.f - fy) * fx;
            float w10 = fy * (1.f - fx), w11 = fy * fx;
            float4 bv[4];
            float ss = 0.f;
#pragma unroll
            for (int i = 0; i < 4; i++) {
                float4 a = *(const float4*)(t00 + i * 64);
                float4 b1 = *(const float4*)(t01 + i * 64);
                float4 c = *(const float4*)(t10 + i * 64);
                float4 d = *(const float4*)(t11 + i * 64);
                float4 v;
                v.x = w00 * a.x + w01 * b1.x + w10 * c.x + w11 * d.x;
                v.y = w00 * a.y + w01 * b1.y + w10 * c.y + w11 * d.y;
                v.z = w00 * a.z + w01 * b1.z + w10 * c.z + w11 * d.z;
                v.w = w00 * a.w + w01 * b1.w + w10 * c.w + w11 * d.w;
                bv[i] = v;
                ss += v.x * v.x + v.y * v.y + v.z * v.z + v.w * v.w;
            }
#pragma unroll
            for (int o = 1; o <= 8; o <<= 1) ss += __shfl_xor(ss, o, 64);
            float inv = __builtin_amdgcn_rsqf(fmaxf(ss, 1e-24f));
            size_t pix = (size_t)(b << 14) + yo * 128 + xo;
            unsigned short* op = qn + pix * Dd + l * 4;
#pragma unroll
            for (int i = 0; i < 4; i++) {
                ushort4 o4;
                o4.x = f2bf(bv[i].x * inv); o4.y = f2bf(bv[i].y * inv);
                o4.z = f2bf(bv[i].z * inv); o4.w = f2bf(bv[i].w * inv);
                *(ushort4*)(op + i * 64) = o4;
            }
        }
    }
}

// ---------- K2: 2D-tiled LDS corr + shuffle softmax + LDS-transposed vector writeout ----------
__global__ __launch_bounds__(512, 4) void corr_block(const unsigned short* __restrict__ qn,
                                                     const unsigned short* __restrict__ kn,
                                                     const float* __restrict__ log_temp,
                                                     unsigned short* __restrict__ xb,
                                                     float* __restrict__ out) {
    constexpr int ASMEM = 308 * 5 * 16;          // 24640 (14x22 halo)
    __shared__ char smem[ASMEM + 128 * 65 * 4];  // + 33280 output transpose tile
    unsigned* sC = (unsigned*)(smem + ASMEM);
    int tid = threadIdx.x;
    int wid = tid >> 6, lane = tid & 63, l15 = lane & 15, quad = lane >> 4;
    int blk = blockIdx.x;                    // 512 = 4 b x 16 ty x 8 tx
    int b = blk >> 7, rem = blk & 127;
    int y0 = (rem >> 3) << 3, x0 = (rem & 7) << 4;
    int y = y0 + wid;

    // zero pad-channels 52..63 of the transpose tile (ordered before use by loop syncs)
#pragma unroll
    for (int i = 0; i < 3; i++) {
        int g = i * 512 + tid;               // 1536 exactly
        int px = g / 12, ch = 52 + g - (g / 12) * 12;
        sC[px * 65 + ch] = 0u;
    }

    const unsigned short* src0; int dst0;
    const unsigned short* src1; int dst1;
    const unsigned short* src2; int dst2; bool hav2;
    {
        int g = tid;
        int px = g >> 2, sub = g & 3;
        int ry = px / 22, rx = px - ry * 22;
        int yy = min(max(y0 - 3 + ry, 0), 127);
        int xx = min(max(x0 - 3 + rx, 0), 127);
        src0 = kn + ((size_t)(b << 14) + yy * 128 + xx) * 256 + sub * 8;
        dst0 = (px * 5 + sub) * 16;
        g = 512 + tid;
        px = g >> 2; sub = g & 3;
        ry = px / 22; rx = px - ry * 22;
        yy = min(max(y0 - 3 + ry, 0), 127);
        xx = min(max(x0 - 3 + rx, 0), 127);
        src1 = kn + ((size_t)(b << 14) + yy * 128 + xx) * 256 + sub * 8;
        dst1 = (px * 5 + sub) * 16;
        g = 1024 + tid;
        hav2 = (g < 1232);
        int gc = hav2 ? g : 1231;
        px = gc >> 2; sub = gc & 3;
        ry = px / 22; rx = px - ry * 22;
        yy = min(max(y0 - 3 + ry, 0), 127);
        xx = min(max(x0 - 3 + rx, 0), 127);
        src2 = kn + ((size_t)(b << 14) + yy * 128 + xx) * 256 + sub * 8;
        dst2 = (px * 5 + sub) * 16;
    }
    int lpixoff[10];
#pragma unroll
    for (int f = 0; f < 10; f++) {
        int p = min(f * 16 + l15, 153);
        int pr = p / 22, pc = p - pr * 22;
        lpixoff[f] = (((wid + pr) * 22 + pc) * 5 + quad) * 16;
    }
    const unsigned short* aptr = qn + ((size_t)(b << 14) + y * 128 + x0 + l15) * 256 + quad * 8;

    f32x4 acc[10];
#pragma unroll
    for (int f = 0; f < 10; f++) acc[f] = (f32x4){0.f, 0.f, 0.f, 0.f};

    uint4 v0 = *(const uint4*)src0;
    uint4 v1 = *(const uint4*)src1;
    uint4 v2 = *(const uint4*)src2;
    s16x8 an = *(const s16x8*)aptr;
    for (int c = 0; c < 8; c++) {
        uint4 w0v = v0, w1v = v1, w2v = v2;
        s16x8 a = an;
        if (c < 7) {
            v0 = *(const uint4*)(src0 + (c + 1) * 32);
            v1 = *(const uint4*)(src1 + (c + 1) * 32);
            v2 = *(const uint4*)(src2 + (c + 1) * 32);
            an = *(const s16x8*)(aptr + (c + 1) * 32);
        }
        __syncthreads();
        *(uint4*)(smem + dst0) = w0v;
        *(uint4*)(smem + dst1) = w1v;
        if (hav2) *(uint4*)(smem + dst2) = w2v;
        __syncthreads();
#pragma unroll
        for (int f = 0; f < 10; f++) {
            s16x8 bf = *(const s16x8*)(smem + lpixoff[f]);
            acc[f] = __builtin_amdgcn_mfma_f32_16x16x32_bf16(a, bf, acc[f], 0, 0, 0);
        }
    }

    float inv_temp = expf(-log_temp[0]);
    float vmax[4] = {-1e30f, -1e30f, -1e30f, -1e30f};
#pragma unroll
    for (int f = 0; f < 10; f++) {
        int n = f * 16 + l15;
        if (n <= 153) {
            int dy = n / 22 - 3;
            int rx = n - (dy + 3) * 22;
#pragma unroll
            for (int i = 0; i < 4; i++) {
                int m = quad * 4 + i;
                int dx = rx - m - 3;
                if ((unsigned)(dx + 3) <= 6u) vmax[i] = fmaxf(vmax[i], acc[f][i]);
            }
        }
    }
#pragma unroll
    for (int o = 1; o <= 8; o <<= 1) {
#pragma unroll
        for (int i = 0; i < 4; i++) vmax[i] = fmaxf(vmax[i], __shfl_xor(vmax[i], o, 64));
    }
    float se[4] = {0, 0, 0, 0}, sey[4] = {0, 0, 0, 0}, sex[4] = {0, 0, 0, 0}, emax[4] = {0, 0, 0, 0};
#pragma unroll
    for (int f = 0; f < 10; f++) {
        int n = f * 16 + l15;
        if (n <= 153) {
            int dy = n / 22 - 3;
            int rx = n - (dy + 3) * 22;
#pragma unroll
            for (int i = 0; i < 4; i++) {
                int m = quad * 4 + i;
                int dx = rx - m - 3;
                if ((unsigned)(dx + 3) <= 6u) {
                    float v = acc[f][i];
                    float e = expf((v - vmax[i]) * inv_temp);
                    se[i] += e;
                    sey[i] += e * (float)dy;
                    sex[i] += e * (float)dx;
                    emax[i] = fmaxf(emax[i], e);
                    sC[(wid * 16 + m) * 65 + 2 + (dy + 3) * 7 + (dx + 3)] = (unsigned)f2bf(v);
                }
            }
        }
    }
#pragma unroll
    for (int o = 1; o <= 8; o <<= 1) {
#pragma unroll
        for (int i = 0; i < 4; i++) {
            se[i] += __shfl_xor(se[i], o, 64);
            sey[i] += __shfl_xor(sey[i], o, 64);
            sex[i] += __shfl_xor(sex[i], o, 64);
            emax[i] = fmaxf(emax[i], __shfl_xor(emax[i], o, 64));
        }
    }
    if (l15 == 0) {
#pragma unroll
        for (int i = 0; i < 4; i++) {
            int m = quad * 4 + i;
            float inv_se = 1.0f / se[i];
            float dyv = sey[i] * inv_se, dxv = sex[i] * inv_se, conf = emax[i] * inv_se;
            int px = wid * 16 + m;
            sC[px * 65 + 0] = (unsigned)f2bf(dyv);
            sC[px * 65 + 1] = (unsigned)f2bf(dxv);
            sC[px * 65 + 51] = (unsigned)f2bf(conf);
            float* op = out + (size_t)b * 5 * HW + y * 128 + x0 + m;
            op[2 * HW] = dyv; op[3 * HW] = dxv; op[4 * HW] = conf;
        }
    }
    __syncthreads();
    // packed coalesced writeout: 128 px x 64 ch bf16 = 1024 uint4
#pragma unroll
    for (int i = 0; i < 2; i++) {
        int t2 = i * 512 + tid;
        int px = t2 >> 3, seg = t2 & 7;
        const unsigned* sp = sC + px * 65 + seg * 8;
        uint4 o;
        o.x = sp[0] | (sp[1] << 16);
        o.y = sp[2] | (sp[3] << 16);
        o.z = sp[4] | (sp[5] << 16);
        o.w = sp[6] | (sp[7] << 16);
        unsigned short* dst = xb + ((size_t)(b * WP + y0 + (px >> 4) + 2) * WP + x0 + (px & 15) + 2) * 64 + seg * 8;
        *(uint4*)dst = o;
    }
}

// ---------- 16x8-tile MFMA conv: full-W-slice staging, 2 syncs per ks chunk ----------
template <int KS, int OC, bool GELU>
__global__ __launch_bounds__(512, 4) void conv_tile(const unsigned short* __restrict__ in,
                                                    const unsigned short* __restrict__ wb,
                                                    const float* __restrict__ bias,
                                                    unsigned short* __restrict__ outp) {
    constexpr int ICP = KS * 32;
    constexpr int NF = OC / 16;
    constexpr int ABYTES = 240 * 64;            // 12x20 halo, 32ch chunk = 15360
    constexpr int WROWS = 25 * OC;
    constexpr int WGRAN = WROWS * 4;
    __shared__ char smem[ABYTES + WROWS * 64];
    int tid = threadIdx.x;
    int wv = tid >> 6, lane = tid & 63, l15 = lane & 15, quad = lane >> 4;
    int blk = blockIdx.x;                       // 512 = 4 b x 16 ty x 8 tx
    int b = blk >> 7, rem = blk & 127;
    int ty = rem >> 3, tx = rem & 7;
    int y0 = ty * 8, x0 = tx * 16;

    f32x4 acc[NF];
#pragma unroll
    for (int g = 0; g < NF; g++) acc[g] = (f32x4){0.f, 0.f, 0.f, 0.f};

    for (int ks = 0; ks < KS; ks++) {
        __syncthreads();           // prior chunk's compute done
#pragma unroll
        for (int i = 0; i < 2; i++) {
            int g = i * 512 + tid;
            if (g < 960) {
                int px = g >> 2, sub = g & 3;
                int r = px / 20, c = px - r * 20;
                *(uint4*)(smem + px * 64 + (((sub ^ (px >> 1)) & 3) << 4)) =
                    *(const uint4*)(in + ((size_t)(b * WP + y0 + r) * WP + x0 + c) * ICP + ks * 32 + sub * 8);
            }
        }
#pragma unroll
        for (int i = 0; i < (WGRAN + 511) / 512; i++) {
            int g = i * 512 + tid;
            if (g < WGRAN) {
                int nl = g >> 2, sub = g & 3;
                *(uint4*)(smem + ABYTES + nl * 64 + (((sub ^ (nl >> 1)) & 3) << 4)) =
                    *(const uint4*)(wb + (size_t)nl * ICP + ks * 32 + sub * 8);
            }
        }
        __syncthreads();
#pragma unroll
        for (int ky = 0; ky < 5; ky++) {
#pragma unroll
            for (int kx = 0; kx < 5; kx++) {
                int px = (wv + ky) * 20 + l15 + kx;
                s16x8 a = *(const s16x8*)(smem + px * 64 + (((quad ^ (px >> 1)) & 3) << 4));
#pragma unroll
                for (int g = 0; g < NF; g++) {
                    int row = (ky * 5 + kx) * OC + g * 16 + l15;
                    s16x8 bf = *(const s16x8*)(smem + ABYTES + row * 64 + (((quad ^ (row >> 1)) & 3) << 4));
                    acc[g] = __builtin_amdgcn_mfma_f32_16x16x32_bf16(a, bf, acc[g], 0, 0, 0);
                }
            }
        }
    }
    size_t orow = ((size_t)(b * WP + y0 + wv + 2) * WP + x0 + 2) * OC;
#pragma unroll
    for (int g = 0; g < NF; g++) {
        float bv = bias[g * 16 + l15];
#pragma unroll
        for (int r = 0; r < 4; r++) {
            int m = quad * 4 + r;
            float v = acc[g][r] + bv;
            if (GELU) v = gelu_exact(v);
            outp[orow + (size_t)m * OC + g * 16 + l15] = f2bf(v);
        }
    }
}

// ---------- final conv (32->2, OC padded 16) + residual + sky scaling ----------
__global__ __launch_bounds__(512, 4) void conv_final_tile(const unsigned short* __restrict__ in,
                                                          const unsigned short* __restrict__ wb,
                                                          const float* __restrict__ bias,
                                                          float* __restrict__ out) {
    constexpr int ICP = 32, OC = 16;
    constexpr int ABYTES = 240 * 64;
    constexpr int WROWS = 25 * OC;              // 400
    constexpr int WGRAN = WROWS * 4;            // 1600
    __shared__ char smem[ABYTES + WROWS * 64];  // 40960
    int tid = threadIdx.x;
    int wv = tid >> 6, lane = tid & 63, l15 = lane & 15, quad = lane >> 4;
    int blk = blockIdx.x;
    int b = blk >> 7, rem = blk & 127;
    int ty = rem >> 3, tx = rem & 7;
    int y0 = ty * 8, x0 = tx * 16;

#pragma unroll
    for (int i = 0; i < 2; i++) {
        int g = i * 512 + tid;
        if (g < 960) {
            int px = g >> 2, sub = g & 3;
            int r = px / 20, c = px - r * 20;
            *(uint4*)(smem + px * 64 + (((sub ^ (px >> 1)) & 3) << 4)) =
                *(const uint4*)(in + ((size_t)(b * WP + y0 + r) * WP + x0 + c) * ICP + sub * 8);
        }
    }
#pragma unroll
    for (int i = 0; i < 4; i++) {
        int g = i * 512 + tid;
        if (g < WGRAN) {
            int nl = g >> 2, sub = g & 3;
            *(uint4*)(smem + ABYTES + nl * 64 + (((sub ^ (nl >> 1)) & 3) << 4)) =
                *(const uint4*)(wb + (size_t)nl * ICP + sub * 8);
        }
    }
    __syncthreads();
    f32x4 acc = (f32x4){0.f, 0.f, 0.f, 0.f};
#pragma unroll
    for (int ky = 0; ky < 5; ky++) {
#pragma unroll
        for (int kx = 0; kx < 5; kx++) {
            int px = (wv + ky) * 20 + l15 + kx;
            s16x8 a = *(const s16x8*)(smem + px * 64 + (((quad ^ (px >> 1)) & 3) << 4));
            int row = (ky * 5 + kx) * OC + l15;
            s16x8 bf = *(const s16x8*)(smem + ABYTES + row * 64 + (((quad ^ (row >> 1)) & 3) << 4));
            acc = __builtin_amdgcn_mfma_f32_16x16x32_bf16(a, bf, acc, 0, 0, 0);
        }
    }
    if (l15 < 2) {
        float bv = bias[l15];
#pragma unroll
        for (int r = 0; r < 4; r++) {
            int m = quad * 4 + r;
            size_t p5 = (size_t)b * 5 * HW + (y0 + wv) * Ww + x0 + m;
            float a = acc[r] + bv;
            if (l15 == 0) {
                float dyv = out[p5 + 2 * HW];
                out[p5 + HW] = (dyv + a) * 1.6f;   // ddec
            } else {
                float dxv = out[p5 + 3 * HW];
                out[p5] = (dxv + a) * 1.6f;        // dra
            }
        }
    }
}

extern "C" void kernel_launch(void* const* d_in, const int* in_sizes, int n_in,
                              void* d_out, int out_size, void* d_ws, size_t ws_size,
                              hipStream_t stream) {
    const float* rub = (const float*)d_in[0];
    const float* vis = (const float*)d_in[1];
    const float* w0 = (const float*)d_in[2];
    const float* b0 = (const float*)d_in[3];
    const float* w1 = (const float*)d_in[4];
    const float* b1 = (const float*)d_in[5];
    const float* w2 = (const float*)d_in[6];
    const float* b2 = (const float*)d_in[7];
    const float* log_temp = (const float*)d_in[8];
    float* out = (float*)d_out;

    char* ws = (char*)d_ws;
    size_t off = 0;
    const size_t PADPIX = (size_t)Bb * WP * WP;     // 69,696
    unsigned short* kn = (unsigned short*)(ws + off); off += (size_t)NPIX * Dd * 2;
    unsigned short* qn = (unsigned short*)(ws + off); off += (size_t)NPIX * Dd * 2;
    unsigned short* xbp = (unsigned short*)(ws + off); off += PADPIX * 64 * 2;   // contiguous
    unsigned short* h1p = (unsigned short*)(ws + off); off += PADPIX * 32 * 2;   //  zero
    unsigned short* h2p = (unsigned short*)(ws + off); off += PADPIX * 32 * 2;   //  region
    unsigned short* wb0 = (unsigned short*)(ws + off); off += 51200 * 2;
    unsigned short* wb1 = (unsigned short*)(ws + off); off += 25600 * 2;
    unsigned short* wb2 = (unsigned short*)(ws + off); off += 12800 * 2;

    setup_norm<<<9826, 256, 0, stream>>>(w0, w1, w2, wb0, wb1, wb2, (uint4*)xbp,
                                         vis, rub, kn, qn);
    corr_block<<<512, 512, 0, stream>>>(qn, kn, log_temp, xbp, out);
    conv_tile<2, 32, true><<<512, 512, 0, stream>>>(xbp, wb0, b0, h1p);
    conv_tile<1, 32, true><<<512, 512, 0, stream>>>(h1p, wb1, b1, h2p);
    conv_final_tile<<<512, 512, 0, stream>>>(h2p, wb2, b2, out);
}

// Round 6
// 191.979 us; speedup vs baseline: 1.2927x; 1.0196x over previous
//
#include <hip/hip_runtime.h>
#include <math.h>

#define Hh 128
#define Ww 128
#define Dd 256
#define Bb 4
#define HW (Hh*Ww)        // 16384
#define NPIX (Bb*HW)      // 65536
#define WP 132            // padded width/height (2-px zero ring)

typedef __attribute__((ext_vector_type(8))) short s16x8;   // 8 bf16 (4 VGPRs)
typedef __attribute__((ext_vector_type(4))) float f32x4;

__device__ __forceinline__ unsigned short f2bf(float f) {
    unsigned u = __float_as_uint(f);
    u += 0x7FFF + ((u >> 16) & 1);
    return (unsigned short)(u >> 16);
}

__device__ __forceinline__ float gelu_exact(float v) {
    return 0.5f * v * (1.0f + erff(v * 0.70710678118654752f));
}

// ring pixel i in [0,1040) -> (y,x) on the 2-px border of a 132x132 image
__device__ __forceinline__ void ring_yx(int i, int& y, int& x) {
    if (i < 264) { y = i / 132; x = i - y * 132; }
    else if (i < 528) { int j = i - 264; int r = j / 132; y = 130 + r; x = j - r * 132; }
    else { int j = i - 528; y = 2 + (j >> 2); int m = j & 3; x = (m < 2) ? m : 128 + m; }
}

// ---------- K0: merged ring-zero + weight transpose + normalize ----------
// blocks 0..609    : ring zeros (66560 granules) + weight transpose (89600)
// blocks 610..4705 : vis -> kn
// blocks 4706..5729: rubin bilinear -> qn via LDS-staged 6x6 token tile
__global__ __launch_bounds__(256) void setup_norm(const float* __restrict__ w0,
                                                  const float* __restrict__ w1,
                                                  const float* __restrict__ w2,
                                                  unsigned short* __restrict__ wb0,
                                                  unsigned short* __restrict__ wb1,
                                                  unsigned short* __restrict__ wb2,
                                                  unsigned short* __restrict__ xbp,
                                                  unsigned short* __restrict__ h1p,
                                                  unsigned short* __restrict__ h2p,
                                                  const float* __restrict__ vis,
                                                  const float* __restrict__ rub,
                                                  unsigned short* __restrict__ kn,
                                                  unsigned short* __restrict__ qn) {
    __shared__ float stok[36 * 260];
    int tid = threadIdx.x;
    int blk = blockIdx.x;
    if (blk < 610) {
        int t = blk * 256 + tid;
        if (t < 66560) {
            uint4 z = (uint4){0, 0, 0, 0};
            if (t < 33280) {
                int img = t / 8320; int r = t - img * 8320; int px = r >> 3, g = r & 7;
                int y, x; ring_yx(px, y, x);
                *(uint4*)(xbp + ((size_t)(img * WP + y) * WP + x) * 64 + g * 8) = z;
            } else {
                int u = t - 33280;
                unsigned short* base = (u < 16640) ? h1p : h2p;
                int v = (u < 16640) ? u : u - 16640;
                int img = v / 4160; int r = v - img * 4160; int px = r >> 2, g = r & 3;
                int y, x; ring_yx(px, y, x);
                *(uint4*)(base + ((size_t)(img * WP + y) * WP + x) * 32 + g * 8) = z;
            }
            return;
        }
        int u = t - 66560;
        if (u < 51200) {
            int tap = u >> 11; int r = u & 2047; int n = r >> 6; int k = r & 63;
            wb0[u] = (k < 52) ? f2bf(w0[n * 1300 + k * 25 + tap]) : (unsigned short)0;
        } else if (u < 76800) {
            int v = u - 51200; int tap = v >> 10; int r = v & 1023; int n = r >> 5; int k = r & 31;
            wb1[v] = f2bf(w1[n * 800 + k * 25 + tap]);
        } else if (u < 89600) {
            int v = u - 76800; int tap = v >> 9; int r = v & 511; int n = r >> 5; int k = r & 31;
            wb2[v] = (n < 2) ? f2bf(w2[n * 800 + k * 25 + tap]) : (unsigned short)0;
        }
        return;
    }
    int nb = blk - 610;
    int g16 = tid >> 4, l = tid & 15;
    if (nb < 4096) {
        int pix = nb * 16 + g16;
        const float* base = vis + (size_t)pix * Dd + l * 4;
        float4 v[4];
#pragma unroll
        for (int i = 0; i < 4; i++) v[i] = *(const float4*)(base + i * 64);
        float ss = 0.f;
#pragma unroll
        for (int i = 0; i < 4; i++)
            ss += v[i].x * v[i].x + v[i].y * v[i].y + v[i].z * v[i].z + v[i].w * v[i].w;
#pragma unroll
        for (int o = 1; o <= 8; o <<= 1) ss += __shfl_xor(ss, o, 64);
        float inv = __builtin_amdgcn_rsqf(fmaxf(ss, 1e-24f));
        unsigned short* op = kn + (size_t)pix * Dd + l * 4;
#pragma unroll
        for (int i = 0; i < 4; i++) {
            ushort4 o4;
            o4.x = f2bf(v[i].x * inv); o4.y = f2bf(v[i].y * inv);
            o4.z = f2bf(v[i].z * inv); o4.w = f2bf(v[i].w * inv);
            *(ushort4*)(op + i * 64) = o4;
        }
    } else {
        int blk2 = nb - 4096;                // 1024 tiles of 8x8 output px
        int b = blk2 >> 8;
        int rem = blk2 & 255;
        int ty = rem >> 4, tx = rem & 15;
        int oy0 = ty * 8, ox0 = tx * 8;
        int rb = ty * 4 - 1, cb = tx * 4 - 1;    // token window base (6x6)
#pragma unroll
        for (int i = 0; i < 9; i++) {
            int g = i * 256 + tid;               // 2304 granules exactly
            int t = g >> 6, c = g & 63;
            int jy = t / 6, jx = t - jy * 6;
            int gy = min(max(rb + jy, 0), 63);
            int gx = min(max(cb + jx, 0), 63);
            *(float4*)&stok[t * 260 + c * 4] =
                *(const float4*)(rub + ((size_t)(b * 4096 + gy * 64 + gx)) * 256 + c * 4);
        }
        __syncthreads();
        for (int k = 0; k < 4; k++) {
            int pp = g16 * 4 + k;
            int r = pp >> 3, c2 = pp & 7;
            int yo = oy0 + r, xo = ox0 + c2;
            float sy = 0.5f * yo - 0.25f, sx = 0.5f * xo - 0.25f;
            float fyf = floorf(sy), fxf = floorf(sx);
            float fy = sy - fyf, fx = sx - fxf;
            int jy0 = (int)fyf - rb, jx0 = (int)fxf - cb;   // in [0,4]
            const float* t00 = &stok[(jy0 * 6 + jx0) * 260 + l * 4];
            const float* t01 = t00 + 260;
            const float* t10 = t00 + 6 * 260;
            const float* t11 = t10 + 260;
            float w00 = (1.f - fy) * (1.f - fx), w01 = (1.f - fy) * fx;
            float w10 = fy * (1.f - fx), w11 = fy * fx;
            float4 bv[4];
            float ss = 0.f;
#pragma unroll
            for (int i = 0; i < 4; i++) {
                float4 a = *(const float4*)(t00 + i * 64);
                float4 b1 = *(const float4*)(t01 + i * 64);
                float4 c = *(const float4*)(t10 + i * 64);
                float4 d = *(const float4*)(t11 + i * 64);
                float4 v;
                v.x = w00 * a.x + w01 * b1.x + w10 * c.x + w11 * d.x;
                v.y = w00 * a.y + w01 * b1.y + w10 * c.y + w11 * d.y;
                v.z = w00 * a.z + w01 * b1.z + w10 * c.z + w11 * d.z;
                v.w = w00 * a.w + w01 * b1.w + w10 * c.w + w11 * d.w;
                bv[i] = v;
                ss += v.x * v.x + v.y * v.y + v.z * v.z + v.w * v.w;
            }
#pragma unroll
            for (int o = 1; o <= 8; o <<= 1) ss += __shfl_xor(ss, o, 64);
            float inv = __builtin_amdgcn_rsqf(fmaxf(ss, 1e-24f));
            size_t pix = (size_t)(b << 14) + yo * 128 + xo;
            unsigned short* op = qn + pix * Dd + l * 4;
#pragma unroll
            for (int i = 0; i < 4; i++) {
                ushort4 o4;
                o4.x = f2bf(bv[i].x * inv); o4.y = f2bf(bv[i].y * inv);
                o4.z = f2bf(bv[i].z * inv); o4.w = f2bf(bv[i].w * inv);
                *(ushort4*)(op + i * 64) = o4;
            }
        }
    }
}

// ---------- K2: 2D-tiled LDS corr + shuffle softmax + LDS-transposed vector writeout ----------
__global__ __launch_bounds__(512, 4) void corr_block(const unsigned short* __restrict__ qn,
                                                     const unsigned short* __restrict__ kn,
                                                     const float* __restrict__ log_temp,
                                                     unsigned short* __restrict__ xb,
                                                     float* __restrict__ out) {
    constexpr int ASMEM = 308 * 5 * 16;          // 24640 (14x22 halo)
    __shared__ char smem[ASMEM + 128 * 65 * 4];  // + 33280 output transpose tile
    unsigned* sC = (unsigned*)(smem + ASMEM);
    int tid = threadIdx.x;
    int wid = tid >> 6, lane = tid & 63, l15 = lane & 15, quad = lane >> 4;
    int blk = blockIdx.x;                    // 512 = 4 b x 16 ty x 8 tx
    int b = blk >> 7, rem = blk & 127;
    int y0 = (rem >> 3) << 3, x0 = (rem & 7) << 4;
    int y = y0 + wid;

    // zero pad-channels 52..63 of the transpose tile (ordered before use by loop syncs)
#pragma unroll
    for (int i = 0; i < 3; i++) {
        int g = i * 512 + tid;               // 1536 exactly
        int px = g / 12, ch = 52 + g - (g / 12) * 12;
        sC[px * 65 + ch] = 0u;
    }

    const unsigned short* src0; int dst0;
    const unsigned short* src1; int dst1;
    const unsigned short* src2; int dst2; bool hav2;
    {
        int g = tid;
        int px = g >> 2, sub = g & 3;
        int ry = px / 22, rx = px - ry * 22;
        int yy = min(max(y0 - 3 + ry, 0), 127);
        int xx = min(max(x0 - 3 + rx, 0), 127);
        src0 = kn + ((size_t)(b << 14) + yy * 128 + xx) * 256 + sub * 8;
        dst0 = (px * 5 + sub) * 16;
        g = 512 + tid;
        px = g >> 2; sub = g & 3;
        ry = px / 22; rx = px - ry * 22;
        yy = min(max(y0 - 3 + ry, 0), 127);
        xx = min(max(x0 - 3 + rx, 0), 127);
        src1 = kn + ((size_t)(b << 14) + yy * 128 + xx) * 256 + sub * 8;
        dst1 = (px * 5 + sub) * 16;
        g = 1024 + tid;
        hav2 = (g < 1232);
        int gc = hav2 ? g : 1231;
        px = gc >> 2; sub = gc & 3;
        ry = px / 22; rx = px - ry * 22;
        yy = min(max(y0 - 3 + ry, 0), 127);
        xx = min(max(x0 - 3 + rx, 0), 127);
        src2 = kn + ((size_t)(b << 14) + yy * 128 + xx) * 256 + sub * 8;
        dst2 = (px * 5 + sub) * 16;
    }
    int lpixoff[10];
#pragma unroll
    for (int f = 0; f < 10; f++) {
        int p = min(f * 16 + l15, 153);
        int pr = p / 22, pc = p - pr * 22;
        lpixoff[f] = (((wid + pr) * 22 + pc) * 5 + quad) * 16;
    }
    const unsigned short* aptr = qn + ((size_t)(b << 14) + y * 128 + x0 + l15) * 256 + quad * 8;

    f32x4 acc[10];
#pragma unroll
    for (int f = 0; f < 10; f++) acc[f] = (f32x4){0.f, 0.f, 0.f, 0.f};

    uint4 v0 = *(const uint4*)src0;
    uint4 v1 = *(const uint4*)src1;
    uint4 v2 = *(const uint4*)src2;
    s16x8 an = *(const s16x8*)aptr;
    for (int c = 0; c < 8; c++) {
        uint4 w0v = v0, w1v = v1, w2v = v2;
        s16x8 a = an;
        if (c < 7) {
            v0 = *(const uint4*)(src0 + (c + 1) * 32);
            v1 = *(const uint4*)(src1 + (c + 1) * 32);
            v2 = *(const uint4*)(src2 + (c + 1) * 32);
            an = *(const s16x8*)(aptr + (c + 1) * 32);
        }
        __syncthreads();
        *(uint4*)(smem + dst0) = w0v;
        *(uint4*)(smem + dst1) = w1v;
        if (hav2) *(uint4*)(smem + dst2) = w2v;
        __syncthreads();
#pragma unroll
        for (int f = 0; f < 10; f++) {
            s16x8 bf = *(const s16x8*)(smem + lpixoff[f]);
            acc[f] = __builtin_amdgcn_mfma_f32_16x16x32_bf16(a, bf, acc[f], 0, 0, 0);
        }
    }

    float inv_temp = expf(-log_temp[0]);
    float vmax[4] = {-1e30f, -1e30f, -1e30f, -1e30f};
#pragma unroll
    for (int f = 0; f < 10; f++) {
        int n = f * 16 + l15;
        if (n <= 153) {
            int dy = n / 22 - 3;
            int rx = n - (dy + 3) * 22;
#pragma unroll
            for (int i = 0; i < 4; i++) {
                int m = quad * 4 + i;
                int dx = rx - m - 3;
                if ((unsigned)(dx + 3) <= 6u) vmax[i] = fmaxf(vmax[i], acc[f][i]);
            }
        }
    }
#pragma unroll
    for (int o = 1; o <= 8; o <<= 1) {
#pragma unroll
        for (int i = 0; i < 4; i++) vmax[i] = fmaxf(vmax[i], __shfl_xor(vmax[i], o, 64));
    }
    float se[4] = {0, 0, 0, 0}, sey[4] = {0, 0, 0, 0}, sex[4] = {0, 0, 0, 0}, emax[4] = {0, 0, 0, 0};
#pragma unroll
    for (int f = 0; f < 10; f++) {
        int n = f * 16 + l15;
        if (n <= 153) {
            int dy = n / 22 - 3;
            int rx = n - (dy + 3) * 22;
#pragma unroll
            for (int i = 0; i < 4; i++) {
                int m = quad * 4 + i;
                int dx = rx - m - 3;
                if ((unsigned)(dx + 3) <= 6u) {
                    float v = acc[f][i];
                    float e = expf((v - vmax[i]) * inv_temp);
                    se[i] += e;
                    sey[i] += e * (float)dy;
                    sex[i] += e * (float)dx;
                    emax[i] = fmaxf(emax[i], e);
                    sC[(wid * 16 + m) * 65 + 2 + (dy + 3) * 7 + (dx + 3)] = (unsigned)f2bf(v);
                }
            }
        }
    }
#pragma unroll
    for (int o = 1; o <= 8; o <<= 1) {
#pragma unroll
        for (int i = 0; i < 4; i++) {
            se[i] += __shfl_xor(se[i], o, 64);
            sey[i] += __shfl_xor(sey[i], o, 64);
            sex[i] += __shfl_xor(sex[i], o, 64);
            emax[i] = fmaxf(emax[i], __shfl_xor(emax[i], o, 64));
        }
    }
    if (l15 == 0) {
#pragma unroll
        for (int i = 0; i < 4; i++) {
            int m = quad * 4 + i;
            float inv_se = 1.0f / se[i];
            float dyv = sey[i] * inv_se, dxv = sex[i] * inv_se, conf = emax[i] * inv_se;
            int px = wid * 16 + m;
            sC[px * 65 + 0] = (unsigned)f2bf(dyv);
            sC[px * 65 + 1] = (unsigned)f2bf(dxv);
            sC[px * 65 + 51] = (unsigned)f2bf(conf);
            float* op = out + (size_t)b * 5 * HW + y * 128 + x0 + m;
            op[2 * HW] = dyv; op[3 * HW] = dxv; op[4 * HW] = conf;
        }
    }
    __syncthreads();
    // packed coalesced writeout: 128 px x 64 ch bf16 = 1024 uint4
#pragma unroll
    for (int i = 0; i < 2; i++) {
        int t2 = i * 512 + tid;
        int px = t2 >> 3, seg = t2 & 7;
        const unsigned* sp = sC + px * 65 + seg * 8;
        uint4 o;
        o.x = sp[0] | (sp[1] << 16);
        o.y = sp[2] | (sp[3] << 16);
        o.z = sp[4] | (sp[5] << 16);
        o.w = sp[6] | (sp[7] << 16);
        unsigned short* dst = xb + ((size_t)(b * WP + y0 + (px >> 4) + 2) * WP + x0 + (px & 15) + 2) * 64 + seg * 8;
        *(uint4*)dst = o;
    }
}

// ---------- 16x8-tile MFMA conv: full-W-slice staging, 2 syncs per ks chunk ----------
template <int KS, int OC, bool GELU>
__global__ __launch_bounds__(512, 4) void conv_tile(const unsigned short* __restrict__ in,
                                                    const unsigned short* __restrict__ wb,
                                                    const float* __restrict__ bias,
                                                    unsigned short* __restrict__ outp) {
    constexpr int ICP = KS * 32;
    constexpr int NF = OC / 16;
    constexpr int ABYTES = 240 * 64;            // 12x20 halo, 32ch chunk = 15360
    constexpr int WROWS = 25 * OC;
    constexpr int WGRAN = WROWS * 4;
    __shared__ char smem[ABYTES + WROWS * 64];
    int tid = threadIdx.x;
    int wv = tid >> 6, lane = tid & 63, l15 = lane & 15, quad = lane >> 4;
    int blk = blockIdx.x;                       // 512 = 4 b x 16 ty x 8 tx
    int b = blk >> 7, rem = blk & 127;
    int ty = rem >> 3, tx = rem & 7;
    int y0 = ty * 8, x0 = tx * 16;

    f32x4 acc[NF];
#pragma unroll
    for (int g = 0; g < NF; g++) acc[g] = (f32x4){0.f, 0.f, 0.f, 0.f};

    for (int ks = 0; ks < KS; ks++) {
        __syncthreads();           // prior chunk's compute done
#pragma unroll
        for (int i = 0; i < 2; i++) {
            int g = i * 512 + tid;
            if (g < 960) {
                int px = g >> 2, sub = g & 3;
                int r = px / 20, c = px - r * 20;
                *(uint4*)(smem + px * 64 + (((sub ^ (px >> 1)) & 3) << 4)) =
                    *(const uint4*)(in + ((size_t)(b * WP + y0 + r) * WP + x0 + c) * ICP + ks * 32 + sub * 8);
            }
        }
#pragma unroll
        for (int i = 0; i < (WGRAN + 511) / 512; i++) {
            int g = i * 512 + tid;
            if (g < WGRAN) {
                int nl = g >> 2, sub = g & 3;
                *(uint4*)(smem + ABYTES + nl * 64 + (((sub ^ (nl >> 1)) & 3) << 4)) =
                    *(const uint4*)(wb + (size_t)nl * ICP + ks * 32 + sub * 8);
            }
        }
        __syncthreads();
#pragma unroll
        for (int ky = 0; ky < 5; ky++) {
#pragma unroll
            for (int kx = 0; kx < 5; kx++) {
                int px = (wv + ky) * 20 + l15 + kx;
                s16x8 a = *(const s16x8*)(smem + px * 64 + (((quad ^ (px >> 1)) & 3) << 4));
#pragma unroll
                for (int g = 0; g < NF; g++) {
                    int row = (ky * 5 + kx) * OC + g * 16 + l15;
                    s16x8 bf = *(const s16x8*)(smem + ABYTES + row * 64 + (((quad ^ (row >> 1)) & 3) << 4));
                    acc[g] = __builtin_amdgcn_mfma_f32_16x16x32_bf16(a, bf, acc[g], 0, 0, 0);
                }
            }
        }
    }
    size_t orow = ((size_t)(b * WP + y0 + wv + 2) * WP + x0 + 2) * OC;
#pragma unroll
    for (int g = 0; g < NF; g++) {
        float bv = bias[g * 16 + l15];
#pragma unroll
        for (int r = 0; r < 4; r++) {
            int m = quad * 4 + r;
            float v = acc[g][r] + bv;
            if (GELU) v = gelu_exact(v);
            outp[orow + (size_t)m * OC + g * 16 + l15] = f2bf(v);
        }
    }
}

// ---------- final conv (32->2, OC padded 16) + residual + sky scaling ----------
__global__ __launch_bounds__(512, 4) void conv_final_tile(const unsigned short* __restrict__ in,
                                                          const unsigned short* __restrict__ wb,
                                                          const float* __restrict__ bias,
                                                          float* __restrict__ out) {
    constexpr int ICP = 32, OC = 16;
    constexpr int ABYTES = 240 * 64;
    constexpr int WROWS = 25 * OC;              // 400
    constexpr int WGRAN = WROWS * 4;            // 1600
    __shared__ char smem[ABYTES + WROWS * 64];  // 40960
    int tid = threadIdx.x;
    int wv = tid >> 6, lane = tid & 63, l15 = lane & 15, quad = lane >> 4;
    int blk = blockIdx.x;
    int b = blk >> 7, rem = blk & 127;
    int ty = rem >> 3, tx = rem & 7;
    int y0 = ty * 8, x0 = tx * 16;

#pragma unroll
    for (int i = 0; i < 2; i++) {
        int g = i * 512 + tid;
        if (g < 960) {
            int px = g >> 2, sub = g & 3;
            int r = px / 20, c = px - r * 20;
            *(uint4*)(smem + px * 64 + (((sub ^ (px >> 1)) & 3) << 4)) =
                *(const uint4*)(in + ((size_t)(b * WP + y0 + r) * WP + x0 + c) * ICP + sub * 8);
        }
    }
#pragma unroll
    for (int i = 0; i < 4; i++) {
        int g = i * 512 + tid;
        if (g < WGRAN) {
            int nl = g >> 2, sub = g & 3;
            *(uint4*)(smem + ABYTES + nl * 64 + (((sub ^ (nl >> 1)) & 3) << 4)) =
                *(const uint4*)(wb + (size_t)nl * ICP + sub * 8);
        }
    }
    __syncthreads();
    f32x4 acc = (f32x4){0.f, 0.f, 0.f, 0.f};
#pragma unroll
    for (int ky = 0; ky < 5; ky++) {
#pragma unroll
        for (int kx = 0; kx < 5; kx++) {
            int px = (wv + ky) * 20 + l15 + kx;
            s16x8 a = *(const s16x8*)(smem + px * 64 + (((quad ^ (px >> 1)) & 3) << 4));
            int row = (ky * 5 + kx) * OC + l15;
            s16x8 bf = *(const s16x8*)(smem + ABYTES + row * 64 + (((quad ^ (row >> 1)) & 3) << 4));
            acc = __builtin_amdgcn_mfma_f32_16x16x32_bf16(a, bf, acc, 0, 0, 0);
        }
    }
    if (l15 < 2) {
        float bv = bias[l15];
#pragma unroll
        for (int r = 0; r < 4; r++) {
            int m = quad * 4 + r;
            size_t p5 = (size_t)b * 5 * HW + (y0 + wv) * Ww + x0 + m;
            float a = acc[r] + bv;
            if (l15 == 0) {
                float dyv = out[p5 + 2 * HW];
                out[p5 + HW] = (dyv + a) * 1.6f;   // ddec
            } else {
                float dxv = out[p5 + 3 * HW];
                out[p5] = (dxv + a) * 1.6f;        // dra
            }
        }
    }
}

extern "C" void kernel_launch(void* const* d_in, const int* in_sizes, int n_in,
                              void* d_out, int out_size, void* d_ws, size_t ws_size,
                              hipStream_t stream) {
    const float* rub = (const float*)d_in[0];
    const float* vis = (const float*)d_in[1];
    const float* w0 = (const float*)d_in[2];
    const float* b0 = (const float*)d_in[3];
    const float* w1 = (const float*)d_in[4];
    const float* b1 = (const float*)d_in[5];
    const float* w2 = (const float*)d_in[6];
    const float* b2 = (const float*)d_in[7];
    const float* log_temp = (const float*)d_in[8];
    float* out = (float*)d_out;

    char* ws = (char*)d_ws;
    size_t off = 0;
    const size_t PADPIX = (size_t)Bb * WP * WP;     // 69,696
    unsigned short* kn = (unsigned short*)(ws + off); off += (size_t)NPIX * Dd * 2;
    unsigned short* qn = (unsigned short*)(ws + off); off += (size_t)NPIX * Dd * 2;
    unsigned short* xbp = (unsigned short*)(ws + off); off += PADPIX * 64 * 2;
    unsigned short* h1p = (unsigned short*)(ws + off); off += PADPIX * 32 * 2;
    unsigned short* h2p = (unsigned short*)(ws + off); off += PADPIX * 32 * 2;
    unsigned short* wb0 = (unsigned short*)(ws + off); off += 51200 * 2;
    unsigned short* wb1 = (unsigned short*)(ws + off); off += 25600 * 2;
    unsigned short* wb2 = (unsigned short*)(ws + off); off += 12800 * 2;

    setup_norm<<<5730, 256, 0, stream>>>(w0, w1, w2, wb0, wb1, wb2,
                                         xbp, h1p, h2p, vis, rub, kn, qn);
    corr_block<<<512, 512, 0, stream>>>(qn, kn, log_temp, xbp, out);
    conv_tile<2, 32, true><<<512, 512, 0, stream>>>(xbp, wb0, b0, h1p);
    conv_tile<1, 32, true><<<512, 512, 0, stream>>>(h1p, wb1, b1, h2p);
    conv_final_tile<<<512, 512, 0, stream>>>(h2p, wb2, b2, out);
}